// Round 1
// baseline (259.943 us; speedup 1.0000x reference)
//
#include <hip/hip_runtime.h>
#include <hip/hip_bf16.h>

#define DEV __device__ __forceinline__

typedef float f32x4 __attribute__((ext_vector_type(4)));
typedef short s16x8 __attribute__((ext_vector_type(8)));
typedef __bf16 bf16x8 __attribute__((ext_vector_type(8)));

DEV bf16x8 as_bf16(s16x8 v) { return __builtin_bit_cast(bf16x8, v); }

DEV unsigned short f2bf(float f) {
    union { __hip_bfloat16 h; unsigned short u; } c;
    c.h = __float2bfloat16(f);
    return c.u;
}

DEV float wave_sum64(float v) {
#pragma unroll
    for (int m = 1; m < 64; m <<= 1) v += __shfl_xor(v, m, 64);
    return v;
}
DEV float grp_max16(float v) {
#pragma unroll
    for (int m = 1; m < 16; m <<= 1) v = fmaxf(v, __shfl_xor(v, m, 64));
    return v;
}
DEV float grp_sum16(float v) {
#pragma unroll
    for (int m = 1; m < 16; m <<= 1) v += __shfl_xor(v, m, 64);
    return v;
}

// ---------------------------------------------------------------------------
// Mask preprocessing: bits[row][w] (u64, bit set = masked).  Quirks:
//  - row with NO masked entries: set diag bit   (torch need_fix)
//  - row with ALL masked: clear diag bit        (equivalent to "diag score=0":
//    softmax over {one finite, rest -inf} puts weight 1.0 on diag either way)
// ---------------------------------------------------------------------------
__global__ __launch_bounds__(256) void gace_mask_k(
    const float* __restrict__ am, unsigned long long* __restrict__ bits)
{
    const int tid = threadIdx.x, wid = tid >> 6, l = tid & 63;
    const int row = blockIdx.x * 4 + wid;              // 0..8191
    const float* mrow = am + (size_t)row * 2048;
    unsigned long long myword = 0, orAll = 0, andAll = ~0ull;
#pragma unroll 4
    for (int w = 0; w < 32; ++w) {
        unsigned long long bal = __ballot(mrow[w * 64 + l] > 0.5f);
        if (w == l) myword = bal;
        orAll |= bal; andAll &= bal;
    }
    const int lrow = row & 2047;
    const int dw = lrow >> 6, dbit = lrow & 63;
    if (l == dw) {
        if (orAll == 0ull) myword |= (1ull << dbit);
        else if (andAll == ~0ull) myword &= ~(1ull << dbit);
    }
    if (l < 32) bits[(size_t)row * 32 + l] = myword;
}

// ---------------------------------------------------------------------------
// ctx = task@tW + priv@pW + dag@dW (+biases), then pre-LN -> x (f32)
// one block(128) per row
// ---------------------------------------------------------------------------
__global__ __launch_bounds__(128) void gace_ctxln_k(
    const float* __restrict__ task, const float* __restrict__ priv, const float* __restrict__ dag,
    const float* __restrict__ tW, const float* __restrict__ tb,
    const float* __restrict__ pW, const float* __restrict__ pb,
    const float* __restrict__ dW, const float* __restrict__ db,
    const float* __restrict__ gam, const float* __restrict__ bet,
    float* __restrict__ x)
{
    const int row = blockIdx.x, d = threadIdx.x;
    const int l = d & 63, w = d >> 6;
    float acc = tb[d] + pb[d] + db[d];
    const float* tf = task + (size_t)row * 15;
#pragma unroll
    for (int j = 0; j < 15; ++j) acc += tf[j] * tW[j * 128 + d];
    const float* pf = priv + (size_t)row * 6;
#pragma unroll
    for (int j = 0; j < 6; ++j) acc += pf[j] * pW[j * 128 + d];
    const float* df = dag + (size_t)row * 4;
#pragma unroll
    for (int j = 0; j < 4; ++j) acc += df[j] * dW[j * 128 + d];

    __shared__ float sh[2], sh2[2];
    float s = acc;
#pragma unroll
    for (int m = 1; m < 64; m <<= 1) s += __shfl_xor(s, m, 64);
    if (l == 0) sh[w] = s;
    __syncthreads();
    const float mean = (sh[0] + sh[1]) * (1.f / 128.f);
    const float dv = acc - mean;
    float s2 = dv * dv;
#pragma unroll
    for (int m = 1; m < 64; m <<= 1) s2 += __shfl_xor(s2, m, 64);
    if (l == 0) sh2[w] = s2;
    __syncthreads();
    const float var = (sh2[0] + sh2[1]) * (1.f / 128.f);
    x[(size_t)row * 128 + d] = dv * rsqrtf(var + 1e-5f) * gam[d] + bet[d];
}

// ---------------------------------------------------------------------------
// LayerNorm f32 x[8192][128] -> bf16 y.  4 waves/block, 1 row per wave.
// ---------------------------------------------------------------------------
__global__ __launch_bounds__(256) void gace_ln_k(
    const float* __restrict__ x, const float* __restrict__ gam, const float* __restrict__ bet,
    unsigned short* __restrict__ y)
{
    const int tid = threadIdx.x, wid = tid >> 6, l = tid & 63;
    const int row = blockIdx.x * 4 + wid;
    const float* xr = x + (size_t)row * 128;
    const float v0 = xr[l], v1 = xr[l + 64];
    const float s = wave_sum64(v0 + v1);
    const float mean = s * (1.f / 128.f);
    const float d0 = v0 - mean, d1 = v1 - mean;
    const float s2 = wave_sum64(d0 * d0 + d1 * d1);
    const float rs = rsqrtf(s2 * (1.f / 128.f) + 1e-5f);
    y[(size_t)row * 128 + l]      = f2bf(d0 * rs * gam[l] + bet[l]);
    y[(size_t)row * 128 + l + 64] = f2bf(d1 * rs * gam[l + 64] + bet[l + 64]);
}

// ---------------------------------------------------------------------------
// GEMM: C[M,N] = A(bf16)[M,K] @ W(f32->bf16)[K,N] + bias.
// 64x64 tile per block (4 waves, 16 rows each), BK=64, mfma 16x16x32 bf16.
// EPI: 0 = store bf16, 1 = exact-GELU + store bf16, 2 = += into f32 xadd (N=128)
// ---------------------------------------------------------------------------
template<int EPI>
__global__ __launch_bounds__(256) void gace_gemm_k(
    const unsigned short* __restrict__ A, int lda,
    const float* __restrict__ W, int ldw,
    const float* __restrict__ bias, int K,
    unsigned short* __restrict__ outb, int ldo,
    float* __restrict__ xadd)
{
    __shared__ __align__(16) unsigned short As[64 * 72];
    __shared__ __align__(16) unsigned short Bs[64 * 72];
    const int tid = threadIdx.x;
    const int wid = tid >> 6, l = tid & 63;
    const int g = l >> 4, c16 = l & 15;
    const int m0 = blockIdx.x * 64, n0 = blockIdx.y * 64;

    f32x4 acc[4];
#pragma unroll
    for (int i = 0; i < 4; ++i) acc[i] = f32x4{0.f, 0.f, 0.f, 0.f};

    for (int k0 = 0; k0 < K; k0 += 64) {
        {
            const int r = tid >> 3, c = (tid & 7) << 3;
            *(s16x8*)&As[r * 72 + c] = *(const s16x8*)&A[(size_t)(m0 + r) * lda + k0 + c];
            *(s16x8*)&As[(r + 32) * 72 + c] = *(const s16x8*)&A[(size_t)(m0 + r + 32) * lda + k0 + c];
        }
#pragma unroll
        for (int i = 0; i < 16; ++i) {
            const int lin = tid + 256 * i;
            const int kk = lin >> 6, n = lin & 63;
            Bs[n * 72 + kk] = f2bf(W[(size_t)(k0 + kk) * ldw + n0 + n]);
        }
        __syncthreads();
#pragma unroll
        for (int kc = 0; kc < 2; ++kc) {
            const s16x8 af = *(const s16x8*)&As[(16 * wid + c16) * 72 + kc * 32 + 8 * g];
#pragma unroll
            for (int ns = 0; ns < 4; ++ns) {
                const s16x8 bfv = *(const s16x8*)&Bs[(16 * ns + c16) * 72 + kc * 32 + 8 * g];
                acc[ns] = __builtin_amdgcn_mfma_f32_16x16x32_bf16(
                    as_bf16(af), as_bf16(bfv), acc[ns], 0, 0, 0);
            }
        }
        __syncthreads();
    }
#pragma unroll
    for (int ns = 0; ns < 4; ++ns) {
        const int n = n0 + ns * 16 + c16;
        const float bv = bias[n];
#pragma unroll
        for (int r = 0; r < 4; ++r) {
            const int row = m0 + 16 * wid + 4 * g + r;
            float v = acc[ns][r] + bv;
            if (EPI == 1) v = v * 0.5f * (1.0f + erff(v * 0.70710678118654752f));
            if (EPI == 2) xadd[(size_t)row * 128 + n] += v;
            else          outb[(size_t)row * ldo + n] = f2bf(v);
        }
    }
}

// ---------------------------------------------------------------------------
// Flash attention.  Block = (b, h, 64 q-rows); 4 waves, 16 q-rows/wave.
// KV tiles of 64 staged in LDS; online softmax in f32; P via per-wave LDS.
// q/k/v/att layout: [b*2048 + l][128] bf16 with head offset h*32.
// ---------------------------------------------------------------------------
__global__ __launch_bounds__(256) void gace_flash_k(
    const unsigned short* __restrict__ Qb,
    const unsigned short* __restrict__ Kb,
    const unsigned short* __restrict__ Vb,
    const unsigned long long* __restrict__ bits,
    unsigned short* __restrict__ att)
{
    constexpr float SCALE = 0.17677669529663687f;   // 1/sqrt(32)
    __shared__ __align__(16) unsigned short Ks[64 * 40];
    __shared__ __align__(16) unsigned short Vt[32 * 72];
    __shared__ __align__(16) unsigned short Pl[4 * 16 * 72];

    const int tid = threadIdx.x;
    const int wid = tid >> 6, l = tid & 63;
    const int g = l >> 4, c16 = l & 15;
    const int bid = blockIdx.x;
    const int q64 = bid & 31, h = (bid >> 5) & 3, b = bid >> 7;
    const size_t base = (size_t)b * 2048;
    const int qb0 = q64 * 64 + wid * 16;

    const s16x8 qf = *(const s16x8*)&Qb[(base + qb0 + c16) * 128 + h * 32 + 8 * g];
    const bf16x8 qa = as_bf16(qf);

    f32x4 oacc[2];
    oacc[0] = f32x4{0.f, 0.f, 0.f, 0.f};
    oacc[1] = f32x4{0.f, 0.f, 0.f, 0.f};
    float m_[4], l_[4];
#pragma unroll
    for (int r = 0; r < 4; ++r) { m_[r] = -1e30f; l_[r] = 0.f; }

    unsigned short* Pw = &Pl[wid * 16 * 72];
    const int sr = tid >> 2, sc = (tid & 3) << 3;

    for (int blk = 0; blk < 32; ++blk) {
        const int kv0 = blk * 64;
        {   // stage K [64][32] and V^T [32][64]
            const s16x8 kv = *(const s16x8*)&Kb[(base + kv0 + sr) * 128 + h * 32 + sc];
            *(s16x8*)&Ks[sr * 40 + sc] = kv;
            union { s16x8 v; unsigned short u[8]; } vv;
            vv.v = *(const s16x8*)&Vb[(base + kv0 + sr) * 128 + h * 32 + sc];
#pragma unroll
            for (int j = 0; j < 8; ++j) Vt[(sc + j) * 72 + sr] = vv.u[j];
        }
        __syncthreads();

        // S = Q K^T  (4 sub-tiles of 16 k-cols)
        f32x4 sac[4];
#pragma unroll
        for (int s = 0; s < 4; ++s) {
            const s16x8 kf = *(const s16x8*)&Ks[(16 * s + c16) * 40 + 8 * g];
            sac[s] = __builtin_amdgcn_mfma_f32_16x16x32_bf16(
                qa, as_bf16(kf), f32x4{0.f, 0.f, 0.f, 0.f}, 0, 0, 0);
        }
        // scale + mask
        float sv[4][4];
#pragma unroll
        for (int r = 0; r < 4; ++r) {
            const unsigned long long wb = bits[(base + qb0 + 4 * g + r) * 32 + blk];
#pragma unroll
            for (int s = 0; s < 4; ++s) {
                float v = sac[s][r] * SCALE;
                if ((wb >> (16 * s + c16)) & 1ull) v = -1e30f;
                sv[s][r] = v;
            }
        }
        // online softmax update (rows live on 16-lane groups)
#pragma unroll
        for (int r = 0; r < 4; ++r) {
            float rm = fmaxf(fmaxf(sv[0][r], sv[1][r]), fmaxf(sv[2][r], sv[3][r]));
            rm = grp_max16(rm);
            const float mn = fmaxf(m_[r], rm);
            const float al = __expf(m_[r] - mn);
            float rs = 0.f;
#pragma unroll
            for (int s = 0; s < 4; ++s) {
                const float p = (sv[s][r] <= -1e29f) ? 0.f : __expf(sv[s][r] - mn);
                sv[s][r] = p; rs += p;
            }
            rs = grp_sum16(rs);
            l_[r] = l_[r] * al + rs;
            m_[r] = mn;
            oacc[0][r] *= al;
            oacc[1][r] *= al;
        }
        // P -> per-wave LDS (bf16), then PV MFMAs
#pragma unroll
        for (int r = 0; r < 4; ++r)
#pragma unroll
            for (int s = 0; s < 4; ++s)
                Pw[(4 * g + r) * 72 + 16 * s + c16] = f2bf(sv[s][r]);
#pragma unroll
        for (int cc = 0; cc < 2; ++cc) {
            const s16x8 pf = *(const s16x8*)&Pw[c16 * 72 + 32 * cc + 8 * g];
#pragma unroll
            for (int ds = 0; ds < 2; ++ds) {
                const s16x8 vf = *(const s16x8*)&Vt[(16 * ds + c16) * 72 + 32 * cc + 8 * g];
                oacc[ds] = __builtin_amdgcn_mfma_f32_16x16x32_bf16(
                    as_bf16(pf), as_bf16(vf), oacc[ds], 0, 0, 0);
            }
        }
        __syncthreads();
    }
#pragma unroll
    for (int ds = 0; ds < 2; ++ds)
#pragma unroll
        for (int r = 0; r < 4; ++r) {
            const float v = oacc[ds][r] / l_[r];
            att[(base + qb0 + 4 * g + r) * 128 + h * 32 + 16 * ds + c16] = f2bf(v);
        }
}

// ---------------------------------------------------------------------------
// Tail A: post-LN each row, partial-sum 64 rows per block -> partial[chunk][128]
// ---------------------------------------------------------------------------
__global__ __launch_bounds__(256) void gace_tailA_k(
    const float* __restrict__ x, const float* __restrict__ gam, const float* __restrict__ bet,
    float* __restrict__ partial)
{
    const int tid = threadIdx.x, wid = tid >> 6, l = tid & 63;
    const int row0 = blockIdx.x * 64 + wid * 16;
    const float g0 = gam[l], g1v = gam[l + 64], b0 = bet[l], b1 = bet[l + 64];
    float a0 = 0.f, a1 = 0.f;
    for (int rr = 0; rr < 16; ++rr) {
        const float* xr = x + (size_t)(row0 + rr) * 128;
        const float v0 = xr[l], v1 = xr[l + 64];
        const float s = wave_sum64(v0 + v1);
        const float mean = s * (1.f / 128.f);
        const float d0 = v0 - mean, d1 = v1 - mean;
        const float s2 = wave_sum64(d0 * d0 + d1 * d1);
        const float rs = rsqrtf(s2 * (1.f / 128.f) + 1e-5f);
        a0 += d0 * rs * g0 + b0;
        a1 += d1 * rs * g1v + b1;
    }
    __shared__ float red[4][128];
    red[wid][l] = a0;
    red[wid][l + 64] = a1;
    __syncthreads();
    if (tid < 128) {
        partial[(size_t)blockIdx.x * 128 + tid] =
            red[0][tid] + red[1][tid] + red[2][tid] + red[3][tid];
    }
}

// ---------------------------------------------------------------------------
// Tail B: fused = mean + 0.1*lg; out = fused @ out_W + out_b   (1 block, 128 thr)
// ---------------------------------------------------------------------------
__global__ __launch_bounds__(128) void gace_tailB_k(
    const float* __restrict__ partial, const float* __restrict__ lg,
    const float* __restrict__ oW, const float* __restrict__ obv,
    float* __restrict__ out)
{
    const int tid = threadIdx.x;
    __shared__ float fused[4][128];
#pragma unroll
    for (int b2 = 0; b2 < 4; ++b2) {
        float s = 0.f;
        for (int c = 0; c < 32; ++c) s += partial[(size_t)(b2 * 32 + c) * 128 + tid];
        fused[b2][tid] = s * (1.f / 2048.f) + 0.1f * lg[b2 * 128 + tid];
    }
    __syncthreads();
#pragma unroll
    for (int b2 = 0; b2 < 4; ++b2) {
        float r = obv[tid];
        for (int d2 = 0; d2 < 128; ++d2) r += fused[b2][d2] * oW[d2 * 128 + tid];
        out[b2 * 128 + tid] = r;
    }
}

// ---------------------------------------------------------------------------
extern "C" void kernel_launch(void* const* d_in, const int* in_sizes, int n_in,
                              void* d_out, int out_size, void* d_ws, size_t ws_size,
                              hipStream_t stream)
{
    (void)in_sizes; (void)n_in; (void)out_size; (void)ws_size;
    const float* local_global = (const float*)d_in[0];
    const float* task   = (const float*)d_in[1];
    const float* priv   = (const float*)d_in[2];
    const float* dag    = (const float*)d_in[3];
    const float* amask  = (const float*)d_in[4];
    const float* task_W = (const float*)d_in[5];
    const float* task_b = (const float*)d_in[6];
    const float* priv_W = (const float*)d_in[7];
    const float* priv_b = (const float*)d_in[8];
    const float* dag_W  = (const float*)d_in[9];
    const float* dag_b  = (const float*)d_in[10];
    const float* pre_g  = (const float*)d_in[11];
    const float* pre_b  = (const float*)d_in[12];
    const float* post_g = (const float*)d_in[13];
    const float* post_b = (const float*)d_in[14];
    const float* out_W  = (const float*)d_in[15];
    const float* out_b  = (const float*)d_in[16];
    const float* qW = (const float*)d_in[17];
    const float* qb = (const float*)d_in[18];
    const float* kW = (const float*)d_in[19];
    const float* kb = (const float*)d_in[20];
    const float* vW = (const float*)d_in[21];
    const float* vb = (const float*)d_in[22];
    const float* oW = (const float*)d_in[23];
    const float* ob = (const float*)d_in[24];
    const float* n1g = (const float*)d_in[25];
    const float* n1b = (const float*)d_in[26];
    const float* n2g = (const float*)d_in[27];
    const float* n2b = (const float*)d_in[28];
    const float* f1W = (const float*)d_in[29];
    const float* f1b = (const float*)d_in[30];
    const float* f2W = (const float*)d_in[31];
    const float* f2b = (const float*)d_in[32];

    char* ws = (char*)d_ws;
    size_t off = 0;
    auto carve = [&](size_t sz) {
        void* p = ws + off;
        off += (sz + 255) & ~(size_t)255;
        return p;
    };
    unsigned long long* bits = (unsigned long long*)carve(8192ull * 32 * 8);  // 2 MB
    float*          x    = (float*)carve(8192ull * 128 * 4);                   // 4 MB
    unsigned short* y    = (unsigned short*)carve(8192ull * 128 * 2);          // 2 MB (also att)
    unsigned short* qbuf = (unsigned short*)carve(8192ull * 128 * 2);
    unsigned short* kbuf = (unsigned short*)carve(8192ull * 128 * 2);
    unsigned short* vbuf = (unsigned short*)carve(8192ull * 128 * 2);
    unsigned short* g1   = (unsigned short*)carve(8192ull * 256 * 2);          // 4 MB
    float*          part = (float*)carve(128ull * 128 * 4);

    gace_mask_k<<<2048, 256, 0, stream>>>(amask, bits);
    gace_ctxln_k<<<8192, 128, 0, stream>>>(task, priv, dag, task_W, task_b,
                                           priv_W, priv_b, dag_W, dag_b,
                                           pre_g, pre_b, x);
    const dim3 gemmN128(128, 2), gemmN256(128, 4);
    for (int i = 0; i < 2; ++i) {
        gace_ln_k<<<2048, 256, 0, stream>>>(x, n1g + i * 128, n1b + i * 128, y);
        gace_gemm_k<0><<<gemmN128, 256, 0, stream>>>(y, 128, qW + i * 16384, 128,
                                                     qb + i * 128, 128, qbuf, 128, nullptr);
        gace_gemm_k<0><<<gemmN128, 256, 0, stream>>>(y, 128, kW + i * 16384, 128,
                                                     kb + i * 128, 128, kbuf, 128, nullptr);
        gace_gemm_k<0><<<gemmN128, 256, 0, stream>>>(y, 128, vW + i * 16384, 128,
                                                     vb + i * 128, 128, vbuf, 128, nullptr);
        gace_flash_k<<<512, 256, 0, stream>>>(qbuf, kbuf, vbuf, bits, y);       // y := att
        gace_gemm_k<2><<<gemmN128, 256, 0, stream>>>(y, 128, oW + i * 16384, 128,
                                                     ob + i * 128, 128, nullptr, 0, x);
        gace_ln_k<<<2048, 256, 0, stream>>>(x, n2g + i * 128, n2b + i * 128, y);
        gace_gemm_k<1><<<gemmN256, 256, 0, stream>>>(y, 128, f1W + i * 32768, 256,
                                                     f1b + i * 256, 128, g1, 256, nullptr);
        gace_gemm_k<2><<<gemmN128, 256, 0, stream>>>(g1, 256, f2W + i * 32768, 128,
                                                     f2b + i * 128, 256, nullptr, 0, x);
    }
    gace_tailA_k<<<128, 256, 0, stream>>>(x, post_g, post_b, part);
    gace_tailB_k<<<1, 128, 0, stream>>>(part, local_global, out_W, out_b, (float*)d_out);
}

// Round 2
// 259.396 us; speedup vs baseline: 1.0021x; 1.0021x over previous
//
#include <hip/hip_runtime.h>
#include <hip/hip_bf16.h>

#define DEV __device__ __forceinline__

typedef float f32x4 __attribute__((ext_vector_type(4)));
typedef short s16x8 __attribute__((ext_vector_type(8)));
typedef __bf16 bf16x8 __attribute__((ext_vector_type(8)));

DEV bf16x8 as_bf16(s16x8 v) { return __builtin_bit_cast(bf16x8, v); }

DEV unsigned short f2bf(float f) {
    union { __hip_bfloat16 h; unsigned short u; } c;
    c.h = __float2bfloat16(f);
    return c.u;
}

DEV float wave_sum64(float v) {
#pragma unroll
    for (int m = 1; m < 64; m <<= 1) v += __shfl_xor(v, m, 64);
    return v;
}
DEV float grp_max16(float v) {
#pragma unroll
    for (int m = 1; m < 16; m <<= 1) v = fmaxf(v, __shfl_xor(v, m, 64));
    return v;
}
DEV float grp_sum16(float v) {
#pragma unroll
    for (int m = 1; m < 16; m <<= 1) v += __shfl_xor(v, m, 64);
    return v;
}

// XOR swizzle: rotates 16B slot within a 128B row; row>>3 term keeps rows that
// share (row&7) (e.g. the 4 rows written by one scatter instr) on distinct slots.
DEV int swz8(int row) { return ((row ^ (row >> 3)) & 7) << 4; }

// ---------------------------------------------------------------------------
// Mask preprocessing: bits[row][w] (u64, bit set = masked).  Quirks:
//  - row with NO masked entries: set diag bit   (torch need_fix)
//  - row with ALL masked: clear diag bit        (softmax over {one finite score,
//    rest -inf} == weight 1.0 on diag, identical to torch's diag-score-0 fixup)
// ---------------------------------------------------------------------------
__global__ __launch_bounds__(256) void gace_mask_k(
    const float* __restrict__ am, unsigned long long* __restrict__ bits)
{
    const int tid = threadIdx.x, wid = tid >> 6, l = tid & 63;
    const int row = blockIdx.x * 4 + wid;              // 0..8191
    const float* mrow = am + (size_t)row * 2048;
    unsigned long long myword = 0, orAll = 0, andAll = ~0ull;
#pragma unroll 4
    for (int w = 0; w < 32; ++w) {
        unsigned long long bal = __ballot(mrow[w * 64 + l] > 0.5f);
        if (w == l) myword = bal;
        orAll |= bal; andAll &= bal;
    }
    const int lrow = row & 2047;
    const int dw = lrow >> 6, dbit = lrow & 63;
    if (l == dw) {
        if (orAll == 0ull) myword |= (1ull << dbit);
        else if (andAll == ~0ull) myword &= ~(1ull << dbit);
    }
    if (l < 32) bits[(size_t)row * 32 + l] = myword;
}

// ---------------------------------------------------------------------------
// ctx = task@tW + priv@pW + dag@dW (+biases), then pre-LN -> x (f32)
// ---------------------------------------------------------------------------
__global__ __launch_bounds__(128) void gace_ctxln_k(
    const float* __restrict__ task, const float* __restrict__ priv, const float* __restrict__ dag,
    const float* __restrict__ tW, const float* __restrict__ tb,
    const float* __restrict__ pW, const float* __restrict__ pb,
    const float* __restrict__ dW, const float* __restrict__ db,
    const float* __restrict__ gam, const float* __restrict__ bet,
    float* __restrict__ x)
{
    const int row = blockIdx.x, d = threadIdx.x;
    const int l = d & 63, w = d >> 6;
    float acc = tb[d] + pb[d] + db[d];
    const float* tf = task + (size_t)row * 15;
#pragma unroll
    for (int j = 0; j < 15; ++j) acc += tf[j] * tW[j * 128 + d];
    const float* pf = priv + (size_t)row * 6;
#pragma unroll
    for (int j = 0; j < 6; ++j) acc += pf[j] * pW[j * 128 + d];
    const float* df = dag + (size_t)row * 4;
#pragma unroll
    for (int j = 0; j < 4; ++j) acc += df[j] * dW[j * 128 + d];

    __shared__ float sh[2], sh2[2];
    float s = acc;
#pragma unroll
    for (int m = 1; m < 64; m <<= 1) s += __shfl_xor(s, m, 64);
    if (l == 0) sh[w] = s;
    __syncthreads();
    const float mean = (sh[0] + sh[1]) * (1.f / 128.f);
    const float dv = acc - mean;
    float s2 = dv * dv;
#pragma unroll
    for (int m = 1; m < 64; m <<= 1) s2 += __shfl_xor(s2, m, 64);
    if (l == 0) sh2[w] = s2;
    __syncthreads();
    const float var = (sh2[0] + sh2[1]) * (1.f / 128.f);
    x[(size_t)row * 128 + d] = dv * rsqrtf(var + 1e-5f) * gam[d] + bet[d];
}

// ---------------------------------------------------------------------------
// LayerNorm f32 x[8192][128] -> bf16 y.  4 waves/block, 1 row per wave.
// ---------------------------------------------------------------------------
__global__ __launch_bounds__(256) void gace_ln_k(
    const float* __restrict__ x, const float* __restrict__ gam, const float* __restrict__ bet,
    unsigned short* __restrict__ y)
{
    const int tid = threadIdx.x, wid = tid >> 6, l = tid & 63;
    const int row = blockIdx.x * 4 + wid;
    const float* xr = x + (size_t)row * 128;
    const float v0 = xr[l], v1 = xr[l + 64];
    const float s = wave_sum64(v0 + v1);
    const float mean = s * (1.f / 128.f);
    const float d0 = v0 - mean, d1 = v1 - mean;
    const float s2 = wave_sum64(d0 * d0 + d1 * d1);
    const float rs = rsqrtf(s2 * (1.f / 128.f) + 1e-5f);
    y[(size_t)row * 128 + l]      = f2bf(d0 * rs * gam[l] + bet[l]);
    y[(size_t)row * 128 + l + 64] = f2bf(d1 * rs * gam[l + 64] + bet[l + 64]);
}

// ---------------------------------------------------------------------------
// GEMM: C[M,N] = (A(bf16)[M,K] @ W(f32->bf16)[K,N] + bias) * scl
// 64x64 tile per block (4 waves), BK=64, mfma 16x16x32 bf16.
// EPI: 0 = store bf16 (scaled), 1 = exact-GELU + store bf16, 2 = += into f32 xadd
// ---------------------------------------------------------------------------
template<int EPI>
__global__ __launch_bounds__(256) void gace_gemm_k(
    const unsigned short* __restrict__ A, int lda,
    const float* __restrict__ W, int ldw,
    const float* __restrict__ bias, int K,
    unsigned short* __restrict__ outb, int ldo,
    float* __restrict__ xadd, float scl)
{
    __shared__ __align__(16) unsigned short As[64 * 72];
    __shared__ __align__(16) unsigned short Bs[64 * 72];
    const int tid = threadIdx.x;
    const int wid = tid >> 6, l = tid & 63;
    const int g = l >> 4, c16 = l & 15;
    const int m0 = blockIdx.x * 64, n0 = blockIdx.y * 64;

    f32x4 acc[4];
#pragma unroll
    for (int i = 0; i < 4; ++i) acc[i] = f32x4{0.f, 0.f, 0.f, 0.f};

    for (int k0 = 0; k0 < K; k0 += 64) {
        {
            const int r = tid >> 3, c = (tid & 7) << 3;
            *(s16x8*)&As[r * 72 + c] = *(const s16x8*)&A[(size_t)(m0 + r) * lda + k0 + c];
            *(s16x8*)&As[(r + 32) * 72 + c] = *(const s16x8*)&A[(size_t)(m0 + r + 32) * lda + k0 + c];
        }
#pragma unroll
        for (int i = 0; i < 16; ++i) {
            const int lin = tid + 256 * i;
            const int kk = lin >> 6, n = lin & 63;
            Bs[n * 72 + kk] = f2bf(W[(size_t)(k0 + kk) * ldw + n0 + n]);
        }
        __syncthreads();
#pragma unroll
        for (int kc = 0; kc < 2; ++kc) {
            const s16x8 af = *(const s16x8*)&As[(16 * wid + c16) * 72 + kc * 32 + 8 * g];
#pragma unroll
            for (int ns = 0; ns < 4; ++ns) {
                const s16x8 bfv = *(const s16x8*)&Bs[(16 * ns + c16) * 72 + kc * 32 + 8 * g];
                acc[ns] = __builtin_amdgcn_mfma_f32_16x16x32_bf16(
                    as_bf16(af), as_bf16(bfv), acc[ns], 0, 0, 0);
            }
        }
        __syncthreads();
    }
#pragma unroll
    for (int ns = 0; ns < 4; ++ns) {
        const int n = n0 + ns * 16 + c16;
        const float bv = bias[n];
#pragma unroll
        for (int r = 0; r < 4; ++r) {
            const int row = m0 + 16 * wid + 4 * g + r;
            float v = acc[ns][r] + bv;
            if (EPI == 0) v *= scl;
            if (EPI == 1) v = v * 0.5f * (1.0f + erff(v * 0.70710678118654752f));
            if (EPI == 2) xadd[(size_t)row * 128 + n] += v;
            else          outb[(size_t)row * ldo + n] = f2bf(v);
        }
    }
}

// ---------------------------------------------------------------------------
// Flash attention, KV-split x4.  Grid = b*h*q64*split = 2048 blocks, 4 waves.
// Each block: 8 KV tiles of 64.  Q pre-scaled by (1/sqrt(32))*log2(e) -> exp2.
// Outputs unnormalized O (f32) + per-row (m, l) for the combine pass.
// ---------------------------------------------------------------------------
__global__ __launch_bounds__(256) void gace_flash2_k(
    const unsigned short* __restrict__ Qb,
    const unsigned short* __restrict__ Kb,
    const unsigned short* __restrict__ Vb,
    const unsigned long long* __restrict__ bits,
    float* __restrict__ Op, float* __restrict__ ml)
{
    __shared__ __align__(16) unsigned short Ks[64 * 40];   // [kv][dh], pad 40
    __shared__ __align__(16) char VtB[32 * 128];           // [dh][kv] bf16, swizzled
    __shared__ __align__(16) char PlB[4 * 16 * 128];       // per-wave P [q][kv], swizzled

    const int tid = threadIdx.x;
    const int wid = tid >> 6, l = tid & 63;
    const int g = l >> 4, c16 = l & 15;
    const int bid = blockIdx.x;
    const int split = bid & 3;
    const int q64 = (bid >> 2) & 31;
    const int h = (bid >> 7) & 3;
    const int b = bid >> 9;
    const size_t base = (size_t)b * 2048;
    const int qb0 = q64 * 64 + wid * 16;

    const s16x8 qf = *(const s16x8*)&Qb[(base + qb0 + c16) * 128 + h * 32 + 8 * g];
    const bf16x8 qa = as_bf16(qf);

    f32x4 oacc[2];
    oacc[0] = f32x4{0.f, 0.f, 0.f, 0.f};
    oacc[1] = f32x4{0.f, 0.f, 0.f, 0.f};
    float m_[4], l_[4];
#pragma unroll
    for (int r = 0; r < 4; ++r) { m_[r] = -1e30f; l_[r] = 0.f; }

    char* Pw = &PlB[wid * 16 * 128];
    const int sr = tid >> 2;            // kv row 0..63
    const int se = (tid & 3) << 3;      // dh elem offset 0,8,16,24

    for (int blk = split * 8; blk < split * 8 + 8; ++blk) {
        const int kv0 = blk * 64;
        {   // stage K [64][32] (padded) and V^T [32][64] (swizzled)
            const s16x8 kv = *(const s16x8*)&Kb[(base + kv0 + sr) * 128 + h * 32 + se];
            *(s16x8*)&Ks[sr * 40 + se] = kv;
            union { s16x8 v; unsigned short u[8]; } vv;
            vv.v = *(const s16x8*)&Vb[(base + kv0 + sr) * 128 + h * 32 + se];
#pragma unroll
            for (int j = 0; j < 8; ++j) {
                const int row = se + j;                               // dh 0..31
                *(unsigned short*)&VtB[row * 128 + ((2 * sr) ^ swz8(row))] = vv.u[j];
            }
        }
        __syncthreads();

        // S = Q K^T  (log2-domain: Q pre-scaled)
        f32x4 sac[4];
#pragma unroll
        for (int s = 0; s < 4; ++s) {
            const s16x8 kf = *(const s16x8*)&Ks[(16 * s + c16) * 40 + 8 * g];
            sac[s] = __builtin_amdgcn_mfma_f32_16x16x32_bf16(
                qa, as_bf16(kf), f32x4{0.f, 0.f, 0.f, 0.f}, 0, 0, 0);
        }
        // mask
        float sv[4][4];
#pragma unroll
        for (int r = 0; r < 4; ++r) {
            const unsigned long long wb = bits[(base + qb0 + 4 * g + r) * 32 + blk];
#pragma unroll
            for (int s = 0; s < 4; ++s) {
                float v = sac[s][r];
                if ((wb >> (16 * s + c16)) & 1ull) v = -1e30f;
                sv[s][r] = v;
            }
        }
        // online softmax (rows live on 16-lane groups), base-2 exponentials
#pragma unroll
        for (int r = 0; r < 4; ++r) {
            float rm = fmaxf(fmaxf(sv[0][r], sv[1][r]), fmaxf(sv[2][r], sv[3][r]));
            rm = grp_max16(rm);
            const float mn = fmaxf(m_[r], rm);
            const float al = exp2f(m_[r] - mn);
            float rs = 0.f;
#pragma unroll
            for (int s = 0; s < 4; ++s) {
                const float p = (sv[s][r] <= -1e29f) ? 0.f : exp2f(sv[s][r] - mn);
                sv[s][r] = p; rs += p;
            }
            rs = grp_sum16(rs);
            l_[r] = l_[r] * al + rs;
            m_[r] = mn;
            oacc[0][r] *= al;
            oacc[1][r] *= al;
        }
        // P -> per-wave LDS (bf16, swizzled), then PV MFMAs
#pragma unroll
        for (int r = 0; r < 4; ++r) {
            const int prow = 4 * g + r;
            const int rswz = swz8(prow);
#pragma unroll
            for (int s = 0; s < 4; ++s)
                *(unsigned short*)&Pw[prow * 128 + ((32 * s + 2 * c16) ^ rswz)] = f2bf(sv[s][r]);
        }
        const int prd = swz8(c16);
#pragma unroll
        for (int cc = 0; cc < 2; ++cc) {
            const s16x8 pf = *(const s16x8*)&Pw[c16 * 128 + ((64 * cc + 16 * g) ^ prd)];
#pragma unroll
            for (int ds = 0; ds < 2; ++ds) {
                const int vrow = 16 * ds + c16;
                const s16x8 vf = *(const s16x8*)&VtB[vrow * 128 + ((64 * cc + 16 * g) ^ swz8(vrow))];
                oacc[ds] = __builtin_amdgcn_mfma_f32_16x16x32_bf16(
                    as_bf16(pf), as_bf16(vf), oacc[ds], 0, 0, 0);
            }
        }
        __syncthreads();
    }
    // epilogue: unnormalized O + (m,l)
#pragma unroll
    for (int ds = 0; ds < 2; ++ds)
#pragma unroll
        for (int r = 0; r < 4; ++r)
            Op[((size_t)split * 8192 + base + qb0 + 4 * g + r) * 128 + h * 32 + 16 * ds + c16]
                = oacc[ds][r];
    if (c16 == 0) {
#pragma unroll
        for (int r = 0; r < 4; ++r) {
            const size_t mo = ((size_t)split * 8192 + base + qb0 + 4 * g + r) * 8 + h * 2;
            ml[mo] = m_[r];
            ml[mo + 1] = l_[r];
        }
    }
}

// ---------------------------------------------------------------------------
// Combine the 4 KV-splits: att = sum_s O_s*2^(m_s-M) / sum_s l_s*2^(m_s-M)
// ---------------------------------------------------------------------------
__global__ __launch_bounds__(256) void gace_comb_k(
    const float* __restrict__ Op, const float* __restrict__ ml,
    unsigned short* __restrict__ y)
{
    const int idx = blockIdx.x * 256 + threadIdx.x;      // over 8192*128
    const int row = idx >> 7, d = idx & 127, h = d >> 5;
    float ms[4];
    float M = -1e30f;
#pragma unroll
    for (int s = 0; s < 4; ++s) {
        ms[s] = ml[((size_t)s * 8192 + row) * 8 + h * 2];
        M = fmaxf(M, ms[s]);
    }
    float L = 0.f, O = 0.f;
#pragma unroll
    for (int s = 0; s < 4; ++s) {
        const float w = exp2f(ms[s] - M);
        L += ml[((size_t)s * 8192 + row) * 8 + h * 2 + 1] * w;
        O += Op[((size_t)s * 8192 + row) * 128 + d] * w;
    }
    y[(size_t)row * 128 + d] = f2bf(O / L);
}

// ---------------------------------------------------------------------------
// Tail A: post-LN each row, partial-sum 64 rows per block
// ---------------------------------------------------------------------------
__global__ __launch_bounds__(256) void gace_tailA_k(
    const float* __restrict__ x, const float* __restrict__ gam, const float* __restrict__ bet,
    float* __restrict__ partial)
{
    const int tid = threadIdx.x, wid = tid >> 6, l = tid & 63;
    const int row0 = blockIdx.x * 64 + wid * 16;
    const float g0 = gam[l], g1v = gam[l + 64], b0 = bet[l], b1 = bet[l + 64];
    float a0 = 0.f, a1 = 0.f;
    for (int rr = 0; rr < 16; ++rr) {
        const float* xr = x + (size_t)(row0 + rr) * 128;
        const float v0 = xr[l], v1 = xr[l + 64];
        const float s = wave_sum64(v0 + v1);
        const float mean = s * (1.f / 128.f);
        const float d0 = v0 - mean, d1 = v1 - mean;
        const float s2 = wave_sum64(d0 * d0 + d1 * d1);
        const float rs = rsqrtf(s2 * (1.f / 128.f) + 1e-5f);
        a0 += d0 * rs * g0 + b0;
        a1 += d1 * rs * g1v + b1;
    }
    __shared__ float red[4][128];
    red[wid][l] = a0;
    red[wid][l + 64] = a1;
    __syncthreads();
    if (tid < 128) {
        partial[(size_t)blockIdx.x * 128 + tid] =
            red[0][tid] + red[1][tid] + red[2][tid] + red[3][tid];
    }
}

// ---------------------------------------------------------------------------
// Tail B: fused = mean + 0.1*lg; out = fused @ out_W + out_b
// ---------------------------------------------------------------------------
__global__ __launch_bounds__(128) void gace_tailB_k(
    const float* __restrict__ partial, const float* __restrict__ lg,
    const float* __restrict__ oW, const float* __restrict__ obv,
    float* __restrict__ out)
{
    const int tid = threadIdx.x;
    __shared__ float fused[4][128];
#pragma unroll
    for (int b2 = 0; b2 < 4; ++b2) {
        float s = 0.f;
        for (int c = 0; c < 32; ++c) s += partial[(size_t)(b2 * 32 + c) * 128 + tid];
        fused[b2][tid] = s * (1.f / 2048.f) + 0.1f * lg[b2 * 128 + tid];
    }
    __syncthreads();
#pragma unroll
    for (int b2 = 0; b2 < 4; ++b2) {
        float r = obv[tid];
        for (int d2 = 0; d2 < 128; ++d2) r += fused[b2][d2] * oW[d2 * 128 + tid];
        out[b2 * 128 + tid] = r;
    }
}

// ---------------------------------------------------------------------------
extern "C" void kernel_launch(void* const* d_in, const int* in_sizes, int n_in,
                              void* d_out, int out_size, void* d_ws, size_t ws_size,
                              hipStream_t stream)
{
    (void)in_sizes; (void)n_in; (void)out_size; (void)ws_size;
    const float* local_global = (const float*)d_in[0];
    const float* task   = (const float*)d_in[1];
    const float* priv   = (const float*)d_in[2];
    const float* dag    = (const float*)d_in[3];
    const float* amask  = (const float*)d_in[4];
    const float* task_W = (const float*)d_in[5];
    const float* task_b = (const float*)d_in[6];
    const float* priv_W = (const float*)d_in[7];
    const float* priv_b = (const float*)d_in[8];
    const float* dag_W  = (const float*)d_in[9];
    const float* dag_b  = (const float*)d_in[10];
    const float* pre_g  = (const float*)d_in[11];
    const float* pre_b  = (const float*)d_in[12];
    const float* post_g = (const float*)d_in[13];
    const float* post_b = (const float*)d_in[14];
    const float* out_W  = (const float*)d_in[15];
    const float* out_b  = (const float*)d_in[16];
    const float* qW = (const float*)d_in[17];
    const float* qb = (const float*)d_in[18];
    const float* kW = (const float*)d_in[19];
    const float* kb = (const float*)d_in[20];
    const float* vW = (const float*)d_in[21];
    const float* vb = (const float*)d_in[22];
    const float* oW = (const float*)d_in[23];
    const float* ob = (const float*)d_in[24];
    const float* n1g = (const float*)d_in[25];
    const float* n1b = (const float*)d_in[26];
    const float* n2g = (const float*)d_in[27];
    const float* n2b = (const float*)d_in[28];
    const float* f1W = (const float*)d_in[29];
    const float* f1b = (const float*)d_in[30];
    const float* f2W = (const float*)d_in[31];
    const float* f2b = (const float*)d_in[32];

    char* ws = (char*)d_ws;
    size_t off = 0;
    auto carve = [&](size_t sz) {
        void* p = ws + off;
        off += (sz + 255) & ~(size_t)255;
        return p;
    };
    unsigned long long* bits = (unsigned long long*)carve(8192ull * 32 * 8);  // 2 MB
    float*          x    = (float*)carve(8192ull * 128 * 4);                   // 4 MB
    unsigned short* y    = (unsigned short*)carve(8192ull * 128 * 2);          // 2 MB (ln out / att)
    unsigned short* qbuf = (unsigned short*)carve(8192ull * 128 * 2);
    unsigned short* kbuf = (unsigned short*)carve(8192ull * 128 * 2);
    unsigned short* vbuf = (unsigned short*)carve(8192ull * 128 * 2);
    unsigned short* g1   = (unsigned short*)carve(8192ull * 256 * 2);          // 4 MB
    float*          part = (float*)carve(128ull * 128 * 4);
    float*          Op   = (float*)carve(4ull * 8192 * 128 * 4);               // 16 MB
    float*          mlb  = (float*)carve(4ull * 8192 * 8 * 4);                 // 1 MB

    constexpr float QSCL = (float)(1.4426950408889634 / 5.656854249492381);    // log2(e)/sqrt(32)

    gace_mask_k<<<2048, 256, 0, stream>>>(amask, bits);
    gace_ctxln_k<<<8192, 128, 0, stream>>>(task, priv, dag, task_W, task_b,
                                           priv_W, priv_b, dag_W, dag_b,
                                           pre_g, pre_b, x);
    const dim3 gemmN128(128, 2), gemmN256(128, 4);
    for (int i = 0; i < 2; ++i) {
        gace_ln_k<<<2048, 256, 0, stream>>>(x, n1g + i * 128, n1b + i * 128, y);
        gace_gemm_k<0><<<gemmN128, 256, 0, stream>>>(y, 128, qW + i * 16384, 128,
                                                     qb + i * 128, 128, qbuf, 128, nullptr, QSCL);
        gace_gemm_k<0><<<gemmN128, 256, 0, stream>>>(y, 128, kW + i * 16384, 128,
                                                     kb + i * 128, 128, kbuf, 128, nullptr, 1.0f);
        gace_gemm_k<0><<<gemmN128, 256, 0, stream>>>(y, 128, vW + i * 16384, 128,
                                                     vb + i * 128, 128, vbuf, 128, nullptr, 1.0f);
        gace_flash2_k<<<2048, 256, 0, stream>>>(qbuf, kbuf, vbuf, bits, Op, mlb);
        gace_comb_k<<<4096, 256, 0, stream>>>(Op, mlb, y);                      // y := att
        gace_gemm_k<2><<<gemmN128, 256, 0, stream>>>(y, 128, oW + i * 16384, 128,
                                                     ob + i * 128, 128, nullptr, 0, x, 1.0f);
        gace_ln_k<<<2048, 256, 0, stream>>>(x, n2g + i * 128, n2b + i * 128, y);
        gace_gemm_k<1><<<gemmN256, 256, 0, stream>>>(y, 128, f1W + i * 32768, 256,
                                                     f1b + i * 256, 128, g1, 256, nullptr, 1.0f);
        gace_gemm_k<2><<<gemmN128, 256, 0, stream>>>(g1, 256, f2W + i * 32768, 128,
                                                     f2b + i * 128, 256, nullptr, 0, x, 1.0f);
    }
    gace_tailA_k<<<128, 256, 0, stream>>>(x, post_g, post_b, part);
    gace_tailB_k<<<1, 128, 0, stream>>>(part, local_global, out_W, out_b, (float*)d_out);
}

// Round 3
// 217.905 us; speedup vs baseline: 1.1929x; 1.1904x over previous
//
#include <hip/hip_runtime.h>
#include <hip/hip_bf16.h>

#define DEV __device__ __forceinline__

typedef float f32x4 __attribute__((ext_vector_type(4)));
typedef short s16x8 __attribute__((ext_vector_type(8)));
typedef __bf16 bf16x8 __attribute__((ext_vector_type(8)));

DEV bf16x8 as_bf16(s16x8 v) { return __builtin_bit_cast(bf16x8, v); }

DEV unsigned short f2bf(float f) {
    union { __hip_bfloat16 h; unsigned short u; } c;
    c.h = __float2bfloat16(f);
    return c.u;
}

// RNE f32->bf16 pair pack (no NaN handling; inputs are finite probabilities/weights)
DEV unsigned f2bf2(float lo, float hi) {
    unsigned ulo = __builtin_bit_cast(unsigned, lo);
    unsigned uhi = __builtin_bit_cast(unsigned, hi);
    ulo = (ulo + 0x7fffu + ((ulo >> 16) & 1u)) >> 16;
    uhi = (uhi + 0x7fffu + ((uhi >> 16) & 1u)) & 0xffff0000u;
    return ulo | uhi;
}

DEV float wave_sum64(float v) {
#pragma unroll
    for (int m = 1; m < 64; m <<= 1) v += __shfl_xor(v, m, 64);
    return v;
}

// XOR swizzle: rotates 16B slot within a 128B row.
DEV int swz8(int row) { return ((row ^ (row >> 3)) & 7) << 4; }

constexpr float QSCL = (float)(1.4426950408889634 / 5.656854249492381);  // log2(e)/sqrt(32)

// ---------------------------------------------------------------------------
// Mask preprocessing: bits[row][w] (u64, bit set = masked).  Quirks:
//  - row with NO masked entries: set diag bit   (torch need_fix)
//  - row with ALL masked: clear diag bit        (softmax over {one finite score,
//    rest -inf} == weight 1.0 on diag, identical to torch's diag-score-0 fixup)
// ---------------------------------------------------------------------------
__global__ __launch_bounds__(256) void gace_mask_k(
    const float* __restrict__ am, unsigned long long* __restrict__ bits)
{
    const int tid = threadIdx.x, wid = tid >> 6, l = tid & 63;
    const int row = blockIdx.x * 4 + wid;              // 0..8191
    const float* mrow = am + (size_t)row * 2048;
    unsigned long long myword = 0, orAll = 0, andAll = ~0ull;
#pragma unroll 4
    for (int w = 0; w < 32; ++w) {
        unsigned long long bal = __ballot(mrow[w * 64 + l] > 0.5f);
        if (w == l) myword = bal;
        orAll |= bal; andAll &= bal;
    }
    const int lrow = row & 2047;
    const int dw = lrow >> 6, dbit = lrow & 63;
    if (l == dw) {
        if (orAll == 0ull) myword |= (1ull << dbit);
        else if (andAll == ~0ull) myword &= ~(1ull << dbit);
    }
    if (l < 32) bits[(size_t)row * 32 + l] = myword;
}

// ---------------------------------------------------------------------------
// Weight prep: f32 [k][n] -> bf16 [n][k] per matrix, per layer; QSCL folded
// into qW; bcat = concat(qb*QSCL, kb, vb) per layer (f32).
// wbf layer block (shorts): q 16384 | k 16384 | v 16384 | o 16384 | f1 32768 | f2 32768
// ---------------------------------------------------------------------------
__global__ __launch_bounds__(256) void gace_prep_k(
    const float* __restrict__ qW, const float* __restrict__ kW,
    const float* __restrict__ vW, const float* __restrict__ oW,
    const float* __restrict__ f1W, const float* __restrict__ f2W,
    const float* __restrict__ qb, const float* __restrict__ kb,
    const float* __restrict__ vb,
    unsigned short* __restrict__ wbf, float* __restrict__ bcat)
{
    const int y = blockIdx.y;
    const int idx = blockIdx.x * 256 + threadIdx.x;
    if (y == 6) {
        if (idx < 2 * 384) {
            const int i = idx / 384, j = idx % 384;
            float v;
            if (j < 128)      v = qb[i * 128 + j] * QSCL;
            else if (j < 256) v = kb[i * 128 + j - 128];
            else              v = vb[i * 128 + j - 256];
            bcat[idx] = v;
        }
        return;
    }
    const float* src; int K_, N_, off; float scl = 1.0f;
    switch (y) {
        case 0:  src = qW;  K_ = 128; N_ = 128; off = 0;      scl = QSCL; break;
        case 1:  src = kW;  K_ = 128; N_ = 128; off = 16384;  break;
        case 2:  src = vW;  K_ = 128; N_ = 128; off = 32768;  break;
        case 3:  src = oW;  K_ = 128; N_ = 128; off = 49152;  break;
        case 4:  src = f1W; K_ = 128; N_ = 256; off = 65536;  break;
        default: src = f2W; K_ = 256; N_ = 128; off = 98304;  break;
    }
    const int per = K_ * N_;
    if (idx >= 2 * per) return;
    const int i = idx / per, rem = idx % per;
    const int n = rem / K_, k = rem % K_;
    wbf[(size_t)i * 131072 + off + n * K_ + k] = f2bf(src[(size_t)i * per + k * N_ + n] * scl);
}

// ---------------------------------------------------------------------------
// ctx = task@tW + priv@pW + dag@dW (+biases), then pre-LN -> x (f32)
// ---------------------------------------------------------------------------
__global__ __launch_bounds__(128) void gace_ctxln_k(
    const float* __restrict__ task, const float* __restrict__ priv, const float* __restrict__ dag,
    const float* __restrict__ tW, const float* __restrict__ tb,
    const float* __restrict__ pW, const float* __restrict__ pb,
    const float* __restrict__ dW, const float* __restrict__ db,
    const float* __restrict__ gam, const float* __restrict__ bet,
    float* __restrict__ x)
{
    const int row = blockIdx.x, d = threadIdx.x;
    const int l = d & 63, w = d >> 6;
    float acc = tb[d] + pb[d] + db[d];
    const float* tf = task + (size_t)row * 15;
#pragma unroll
    for (int j = 0; j < 15; ++j) acc += tf[j] * tW[j * 128 + d];
    const float* pf = priv + (size_t)row * 6;
#pragma unroll
    for (int j = 0; j < 6; ++j) acc += pf[j] * pW[j * 128 + d];
    const float* df = dag + (size_t)row * 4;
#pragma unroll
    for (int j = 0; j < 4; ++j) acc += df[j] * dW[j * 128 + d];

    __shared__ float sh[2], sh2[2];
    float s = acc;
#pragma unroll
    for (int m = 1; m < 64; m <<= 1) s += __shfl_xor(s, m, 64);
    if (l == 0) sh[w] = s;
    __syncthreads();
    const float mean = (sh[0] + sh[1]) * (1.f / 128.f);
    const float dv = acc - mean;
    float s2 = dv * dv;
#pragma unroll
    for (int m = 1; m < 64; m <<= 1) s2 += __shfl_xor(s2, m, 64);
    if (l == 0) sh2[w] = s2;
    __syncthreads();
    const float var = (sh2[0] + sh2[1]) * (1.f / 128.f);
    x[(size_t)row * 128 + d] = dv * rsqrtf(var + 1e-5f) * gam[d] + bet[d];
}

// ---------------------------------------------------------------------------
// LayerNorm f32 x[8192][128] -> bf16 y.  4 waves/block, 1 row per wave.
// ---------------------------------------------------------------------------
__global__ __launch_bounds__(256) void gace_ln_k(
    const float* __restrict__ x, const float* __restrict__ gam, const float* __restrict__ bet,
    unsigned short* __restrict__ y)
{
    const int tid = threadIdx.x, wid = tid >> 6, l = tid & 63;
    const int row = blockIdx.x * 4 + wid;
    const float* xr = x + (size_t)row * 128;
    const float v0 = xr[l], v1 = xr[l + 64];
    const float s = wave_sum64(v0 + v1);
    const float mean = s * (1.f / 128.f);
    const float d0 = v0 - mean, d1 = v1 - mean;
    const float s2 = wave_sum64(d0 * d0 + d1 * d1);
    const float rs = rsqrtf(s2 * (1.f / 128.f) + 1e-5f);
    y[(size_t)row * 128 + l]      = f2bf(d0 * rs * gam[l] + bet[l]);
    y[(size_t)row * 128 + l + 64] = f2bf(d1 * rs * gam[l + 64] + bet[l + 64]);
}

// ---------------------------------------------------------------------------
// Direct GEMM, no LDS, no barriers: C[M,Ntot] = A(bf16)[M,K] @ Wt(bf16)[Ntot][K]^T + bias
// Block: 4 waves, each 16 m-rows x 64 n-cols; grid (M/64, Ntot/64).
// EPI: 0 = store bf16; 1 = exact-GELU + store bf16; 2 = += into f32 xadd (N=128)
// ---------------------------------------------------------------------------
template<int EPI, int KD>
__global__ __launch_bounds__(256) void gace_dgemm_k(
    const unsigned short* __restrict__ A, int lda,
    const unsigned short* __restrict__ Wt,
    const float* __restrict__ bias,
    unsigned short* __restrict__ outb, int ldo,
    float* __restrict__ xadd)
{
    const int tid = threadIdx.x;
    const int wid = tid >> 6, l = tid & 63;
    const int g = (l >> 4) & 3, c16 = l & 15;
    const int m0 = blockIdx.x * 64 + wid * 16;
    const int n0 = blockIdx.y * 64;

    s16x8 af[KD / 32];
#pragma unroll
    for (int kc = 0; kc < KD / 32; ++kc)
        af[kc] = *(const s16x8*)&A[(size_t)(m0 + c16) * lda + kc * 32 + 8 * g];

    f32x4 acc[4];
#pragma unroll
    for (int i = 0; i < 4; ++i) acc[i] = f32x4{0.f, 0.f, 0.f, 0.f};

#pragma unroll
    for (int ns = 0; ns < 4; ++ns) {
        const unsigned short* wrow = Wt + (size_t)(n0 + 16 * ns + c16) * KD;
#pragma unroll
        for (int kc = 0; kc < KD / 32; ++kc) {
            const s16x8 bfv = *(const s16x8*)&wrow[kc * 32 + 8 * g];
            acc[ns] = __builtin_amdgcn_mfma_f32_16x16x32_bf16(
                as_bf16(af[kc]), as_bf16(bfv), acc[ns], 0, 0, 0);
        }
    }
#pragma unroll
    for (int ns = 0; ns < 4; ++ns) {
        const int n = n0 + ns * 16 + c16;
        const float bv = bias[n];
#pragma unroll
        for (int r = 0; r < 4; ++r) {
            const int row = m0 + 4 * g + r;
            float v = acc[ns][r] + bv;
            if (EPI == 1) v = v * 0.5f * (1.0f + erff(v * 0.70710678118654752f));
            if (EPI == 2) xadd[(size_t)row * 128 + n] += v;
            else          outb[(size_t)row * ldo + n] = f2bf(v);
        }
    }
}

// ---------------------------------------------------------------------------
// Flash attention v3: swapped QK^T (scores lane-local per q-row) + permuted
// K staging so P feeds PV directly from registers.  KV-split x4.
// QKV: [8192][384] bf16 (q|k|v), Q pre-scaled by log2(e)/sqrt(32).
// Per block: 4 waves x 16 q-rows; 8 KV tiles of 64; single-buffer LDS.
// ---------------------------------------------------------------------------
__global__ __launch_bounds__(256) void gace_flash3_k(
    const unsigned short* __restrict__ QKV,
    const unsigned long long* __restrict__ bits,
    float* __restrict__ Op, float* __restrict__ ml)
{
    __shared__ __align__(16) unsigned short Ks[64 * 40];   // [perm kv][dh], pitch 40
    __shared__ __align__(16) char VtB[32 * 128];           // [dh][kv] bf16, swizzled

    const int tid = threadIdx.x;
    const int wid = tid >> 6, l = tid & 63;
    const int g = (l >> 4) & 3, c16 = l & 15;
    const int bid = blockIdx.x;
    const int split = bid & 3;
    const int q64 = (bid >> 2) & 31;
    const int h = (bid >> 7) & 3;
    const int b = bid >> 9;
    const size_t base = (size_t)b * 2048;
    const int qb0 = q64 * 64 + wid * 16;

    // Q fragment (B-operand): row q = qb0+c16, dh chunk 8g.  (Q pre-scaled.)
    const s16x8 qf = *(const s16x8*)&QKV[(base + qb0 + c16) * 384 + h * 32 + 8 * g];
    const bf16x8 qa = as_bf16(qf);

    f32x4 oacc[2];
    oacc[0] = f32x4{0.f, 0.f, 0.f, 0.f};
    oacc[1] = f32x4{0.f, 0.f, 0.f, 0.f};
    float m_ = -1e30f, l_ = 0.f;            // for q-row qb0 + c16 (replicated x4 g)

    const int sr = tid >> 2;                // kv row 0..63
    const int se = (tid & 3) << 3;          // dh elem 0,8,16,24
    // permuted K LDS row: kv=32s1+8g'+4s0+r  ->  i=32s1+16s0+4g'+r
    const int pr = (sr & 32) | ((sr & 4) << 2) | ((sr & 24) >> 1) | (sr & 3);

    // prologue: load + stage tile 0
    int kv0 = split * 512;
    s16x8 kreg = *(const s16x8*)&QKV[(base + kv0 + sr) * 384 + 128 + h * 32 + se];
    s16x8 vreg = *(const s16x8*)&QKV[(base + kv0 + sr) * 384 + 256 + h * 32 + se];
    *(s16x8*)&Ks[pr * 40 + se] = kreg;
    {
        union { s16x8 v; unsigned short u[8]; } vv; vv.v = vreg;
#pragma unroll
        for (int j = 0; j < 8; ++j) {
            const int row = se + j;
            *(unsigned short*)&VtB[row * 128 + ((2 * sr) ^ swz8(row))] = vv.u[j];
        }
    }
    __syncthreads();

    for (int t = 0; t < 8; ++t) {
        const int blk = split * 8 + t;
        if (t < 7) {    // issue next-tile loads (overlap with compute)
            const int kv1 = (blk + 1) * 64;
            kreg = *(const s16x8*)&QKV[(base + kv1 + sr) * 384 + 128 + h * 32 + se];
            vreg = *(const s16x8*)&QKV[(base + kv1 + sr) * 384 + 256 + h * 32 + se];
        }
        // S^T = K Q^T : lane (g,c16) holds scores for q=qb0+c16,
        // kv = 32*(s>>1) + 8*g + 4*(s&1) + r   (via the pi-permuted staging)
        f32x4 sac[4];
#pragma unroll
        for (int s = 0; s < 4; ++s) {
            const s16x8 kf = *(const s16x8*)&Ks[(16 * s + c16) * 40 + 8 * g];
            sac[s] = __builtin_amdgcn_mfma_f32_16x16x32_bf16(
                as_bf16(kf), qa, f32x4{0.f, 0.f, 0.f, 0.f}, 0, 0, 0);
        }
        // mask (constant-shift extracts after one wb>>8g)
        const unsigned long long wb = bits[(base + qb0 + c16) * 32 + blk];
        const unsigned long long wbg = wb >> (8 * g);
        const unsigned wlo = (unsigned)wbg, whi = (unsigned)(wbg >> 32);
        float sv[4][4];
#pragma unroll
        for (int s = 0; s < 4; ++s) {
            const unsigned word = (s < 2) ? wlo : whi;
#pragma unroll
            for (int r = 0; r < 4; ++r) {
                const int bit = 4 * (s & 1) + r;
                sv[s][r] = ((word >> bit) & 1u) ? -1e30f : sac[s][r];
            }
        }
        // row max: in-lane tree + cross-g (xor 16, 32)
        float rm = sv[0][0];
#pragma unroll
        for (int s = 0; s < 4; ++s)
#pragma unroll
            for (int r = 0; r < 4; ++r) rm = fmaxf(rm, sv[s][r]);
        rm = fmaxf(rm, __shfl_xor(rm, 16, 64));
        rm = fmaxf(rm, __shfl_xor(rm, 32, 64));
        const float mn = fmaxf(m_, rm);
        const float al = exp2f(m_ - mn);
        m_ = mn;
        // p = exp2(s - mn); masked entries underflow to 0 (no guard needed)
        float rs = 0.f;
#pragma unroll
        for (int s = 0; s < 4; ++s)
#pragma unroll
            for (int r = 0; r < 4; ++r) {
                const float p = exp2f(sv[s][r] - mn);
                sv[s][r] = p; rs += p;
            }
        rs += __shfl_xor(rs, 16, 64);
        rs += __shfl_xor(rs, 32, 64);
        l_ = l_ * al + rs;
        // rescale O by the al of each OUTPUT q-row (4g+r), pulled from lane c16=4g+r
#pragma unroll
        for (int r = 0; r < 4; ++r) {
            const float als = __shfl(al, (l & 48) | (4 * g + r), 64);
            oacc[0][r] *= als;
            oacc[1][r] *= als;
        }
        // pack P (lane-local!) and PV
#pragma unroll
        for (int cc = 0; cc < 2; ++cc) {
            union { s16x8 v; unsigned d[4]; } pa;
            pa.d[0] = f2bf2(sv[2 * cc][0], sv[2 * cc][1]);
            pa.d[1] = f2bf2(sv[2 * cc][2], sv[2 * cc][3]);
            pa.d[2] = f2bf2(sv[2 * cc + 1][0], sv[2 * cc + 1][1]);
            pa.d[3] = f2bf2(sv[2 * cc + 1][2], sv[2 * cc + 1][3]);
#pragma unroll
            for (int ds = 0; ds < 2; ++ds) {
                const int vrow = 16 * ds + c16;
                const s16x8 vf = *(const s16x8*)&VtB[vrow * 128 + ((64 * cc + 16 * g) ^ swz8(vrow))];
                oacc[ds] = __builtin_amdgcn_mfma_f32_16x16x32_bf16(
                    as_bf16(pa.v), as_bf16(vf), oacc[ds], 0, 0, 0);
            }
        }
        // stage next tile
        if (t < 7) {
            __syncthreads();
            *(s16x8*)&Ks[pr * 40 + se] = kreg;
            union { s16x8 v; unsigned short u[8]; } vv; vv.v = vreg;
#pragma unroll
            for (int j = 0; j < 8; ++j) {
                const int row = se + j;
                *(unsigned short*)&VtB[row * 128 + ((2 * sr) ^ swz8(row))] = vv.u[j];
            }
            __syncthreads();
        }
    }
    // epilogue: unnormalized O + (m,l)
#pragma unroll
    for (int ds = 0; ds < 2; ++ds)
#pragma unroll
        for (int r = 0; r < 4; ++r)
            Op[((size_t)split * 8192 + base + qb0 + 4 * g + r) * 128 + h * 32 + 16 * ds + c16]
                = oacc[ds][r];
    if (l < 16) {
        const size_t mo = ((size_t)split * 8192 + base + qb0 + l) * 8 + h * 2;
        ml[mo] = m_;
        ml[mo + 1] = l_;
    }
}

// ---------------------------------------------------------------------------
// Combine the 4 KV-splits: att = sum_s O_s*2^(m_s-M) / sum_s l_s*2^(m_s-M)
// ---------------------------------------------------------------------------
__global__ __launch_bounds__(256) void gace_comb_k(
    const float* __restrict__ Op, const float* __restrict__ ml,
    unsigned short* __restrict__ y)
{
    const int idx = blockIdx.x * 256 + threadIdx.x;      // over 8192*128
    const int row = idx >> 7, d = idx & 127, h = d >> 5;
    float ms[4];
    float M = -1e30f;
#pragma unroll
    for (int s = 0; s < 4; ++s) {
        ms[s] = ml[((size_t)s * 8192 + row) * 8 + h * 2];
        M = fmaxf(M, ms[s]);
    }
    float L = 0.f, O = 0.f;
#pragma unroll
    for (int s = 0; s < 4; ++s) {
        const float w = exp2f(ms[s] - M);
        L += ml[((size_t)s * 8192 + row) * 8 + h * 2 + 1] * w;
        O += Op[((size_t)s * 8192 + row) * 128 + d] * w;
    }
    y[(size_t)row * 128 + d] = f2bf(O / L);
}

// ---------------------------------------------------------------------------
// Tail A: post-LN each row, partial-sum 64 rows per block
// ---------------------------------------------------------------------------
__global__ __launch_bounds__(256) void gace_tailA_k(
    const float* __restrict__ x, const float* __restrict__ gam, const float* __restrict__ bet,
    float* __restrict__ partial)
{
    const int tid = threadIdx.x, wid = tid >> 6, l = tid & 63;
    const int row0 = blockIdx.x * 64 + wid * 16;
    const float g0 = gam[l], g1v = gam[l + 64], b0 = bet[l], b1 = bet[l + 64];
    float a0 = 0.f, a1 = 0.f;
    for (int rr = 0; rr < 16; ++rr) {
        const float* xr = x + (size_t)(row0 + rr) * 128;
        const float v0 = xr[l], v1 = xr[l + 64];
        const float s = wave_sum64(v0 + v1);
        const float mean = s * (1.f / 128.f);
        const float d0 = v0 - mean, d1 = v1 - mean;
        const float s2 = wave_sum64(d0 * d0 + d1 * d1);
        const float rs = rsqrtf(s2 * (1.f / 128.f) + 1e-5f);
        a0 += d0 * rs * g0 + b0;
        a1 += d1 * rs * g1v + b1;
    }
    __shared__ float red[4][128];
    red[wid][l] = a0;
    red[wid][l + 64] = a1;
    __syncthreads();
    if (tid < 128) {
        partial[(size_t)blockIdx.x * 128 + tid] =
            red[0][tid] + red[1][tid] + red[2][tid] + red[3][tid];
    }
}

// ---------------------------------------------------------------------------
// Tail B: fused = mean + 0.1*lg; out = fused @ out_W + out_b
// ---------------------------------------------------------------------------
__global__ __launch_bounds__(128) void gace_tailB_k(
    const float* __restrict__ partial, const float* __restrict__ lg,
    const float* __restrict__ oW, const float* __restrict__ obv,
    float* __restrict__ out)
{
    const int tid = threadIdx.x;
    __shared__ float fused[4][128];
#pragma unroll
    for (int b2 = 0; b2 < 4; ++b2) {
        float s = 0.f;
        for (int c = 0; c < 32; ++c) s += partial[(size_t)(b2 * 32 + c) * 128 + tid];
        fused[b2][tid] = s * (1.f / 2048.f) + 0.1f * lg[b2 * 128 + tid];
    }
    __syncthreads();
#pragma unroll
    for (int b2 = 0; b2 < 4; ++b2) {
        float r = obv[tid];
        for (int d2 = 0; d2 < 128; ++d2) r += fused[b2][d2] * oW[d2 * 128 + tid];
        out[b2 * 128 + tid] = r;
    }
}

// ---------------------------------------------------------------------------
extern "C" void kernel_launch(void* const* d_in, const int* in_sizes, int n_in,
                              void* d_out, int out_size, void* d_ws, size_t ws_size,
                              hipStream_t stream)
{
    (void)in_sizes; (void)n_in; (void)out_size; (void)ws_size;
    const float* local_global = (const float*)d_in[0];
    const float* task   = (const float*)d_in[1];
    const float* priv   = (const float*)d_in[2];
    const float* dag    = (const float*)d_in[3];
    const float* amask  = (const float*)d_in[4];
    const float* task_W = (const float*)d_in[5];
    const float* task_b = (const float*)d_in[6];
    const float* priv_W = (const float*)d_in[7];
    const float* priv_b = (const float*)d_in[8];
    const float* dag_W  = (const float*)d_in[9];
    const float* dag_b  = (const float*)d_in[10];
    const float* pre_g  = (const float*)d_in[11];
    const float* pre_b  = (const float*)d_in[12];
    const float* post_g = (const float*)d_in[13];
    const float* post_b = (const float*)d_in[14];
    const float* out_W  = (const float*)d_in[15];
    const float* out_b  = (const float*)d_in[16];
    const float* qW = (const float*)d_in[17];
    const float* qb = (const float*)d_in[18];
    const float* kW = (const float*)d_in[19];
    const float* kb = (const float*)d_in[20];
    const float* vW = (const float*)d_in[21];
    const float* vb = (const float*)d_in[22];
    const float* oW = (const float*)d_in[23];
    const float* ob = (const float*)d_in[24];
    const float* n1g = (const float*)d_in[25];
    const float* n1b = (const float*)d_in[26];
    const float* n2g = (const float*)d_in[27];
    const float* n2b = (const float*)d_in[28];
    const float* f1W = (const float*)d_in[29];
    const float* f1b = (const float*)d_in[30];
    const float* f2W = (const float*)d_in[31];
    const float* f2b = (const float*)d_in[32];

    char* ws = (char*)d_ws;
    size_t off = 0;
    auto carve = [&](size_t sz) {
        void* p = ws + off;
        off += (sz + 255) & ~(size_t)255;
        return p;
    };
    unsigned long long* bits = (unsigned long long*)carve(8192ull * 32 * 8);  // 2 MB
    float*          x    = (float*)carve(8192ull * 128 * 4);                   // 4 MB
    unsigned short* y    = (unsigned short*)carve(8192ull * 128 * 2);          // 2 MB (ln out / att)
    unsigned short* qkv  = (unsigned short*)carve(8192ull * 384 * 2);          // 6 MB
    unsigned short* g1   = (unsigned short*)carve(8192ull * 256 * 2);          // 4 MB
    float*          part = (float*)carve(128ull * 128 * 4);
    float*          Op   = (float*)carve(4ull * 8192 * 128 * 4);               // 16 MB
    float*          mlb  = (float*)carve(4ull * 8192 * 8 * 4);                 // 1 MB
    unsigned short* wbf  = (unsigned short*)carve(2ull * 131072 * 2);          // 512 KB
    float*          bcat = (float*)carve(2ull * 384 * 4);

    gace_prep_k<<<dim3(256, 7), 256, 0, stream>>>(qW, kW, vW, oW, f1W, f2W,
                                                  qb, kb, vb, wbf, bcat);
    gace_mask_k<<<2048, 256, 0, stream>>>(amask, bits);
    gace_ctxln_k<<<8192, 128, 0, stream>>>(task, priv, dag, task_W, task_b,
                                           priv_W, priv_b, dag_W, dag_b,
                                           pre_g, pre_b, x);
    for (int i = 0; i < 2; ++i) {
        const unsigned short* wl = wbf + (size_t)i * 131072;
        gace_ln_k<<<2048, 256, 0, stream>>>(x, n1g + i * 128, n1b + i * 128, y);
        gace_dgemm_k<0, 128><<<dim3(128, 6), 256, 0, stream>>>(
            y, 128, wl, bcat + i * 384, qkv, 384, nullptr);
        gace_flash3_k<<<2048, 256, 0, stream>>>(qkv, bits, Op, mlb);
        gace_comb_k<<<4096, 256, 0, stream>>>(Op, mlb, y);
        gace_dgemm_k<2, 128><<<dim3(128, 2), 256, 0, stream>>>(
            y, 128, wl + 49152, ob + i * 128, nullptr, 0, x);
        gace_ln_k<<<2048, 256, 0, stream>>>(x, n2g + i * 128, n2b + i * 128, y);
        gace_dgemm_k<1, 128><<<dim3(128, 4), 256, 0, stream>>>(
            y, 128, wl + 65536, f1b + i * 256, g1, 256, nullptr);
        gace_dgemm_k<2, 256><<<dim3(128, 2), 256, 0, stream>>>(
            g1, 256, wl + 98304, f2b + i * 128, nullptr, 0, x);
    }
    gace_tailA_k<<<128, 256, 0, stream>>>(x, post_g, post_b, part);
    gace_tailB_k<<<1, 128, 0, stream>>>(part, local_global, out_W, out_b, (float*)d_out);
}

// Round 4
// 189.111 us; speedup vs baseline: 1.3745x; 1.1523x over previous
//
#include <hip/hip_runtime.h>
#include <hip/hip_bf16.h>

#define DEV __device__ __forceinline__

typedef float f32x4 __attribute__((ext_vector_type(4)));
typedef float f32x16 __attribute__((ext_vector_type(16)));
typedef short s16x8 __attribute__((ext_vector_type(8)));
typedef __bf16 bf16x8 __attribute__((ext_vector_type(8)));

DEV bf16x8 as_bf16(s16x8 v) { return __builtin_bit_cast(bf16x8, v); }

DEV unsigned short f2bf(float f) {
    union { __hip_bfloat16 h; unsigned short u; } c;
    c.h = __float2bfloat16(f);
    return c.u;
}

// RNE f32->bf16 pair pack (finite inputs only)
DEV unsigned f2bf2(float lo, float hi) {
    unsigned ulo = __builtin_bit_cast(unsigned, lo);
    unsigned uhi = __builtin_bit_cast(unsigned, hi);
    ulo = (ulo + 0x7fffu + ((ulo >> 16) & 1u)) >> 16;
    uhi = (uhi + 0x7fffu + ((uhi >> 16) & 1u)) & 0xffff0000u;
    return ulo | uhi;
}

DEV float wave_sum64(float v) {
#pragma unroll
    for (int m = 1; m < 64; m <<= 1) v += __shfl_xor(v, m, 64);
    return v;
}

// XOR swizzle: rotates 16B slot within a 128B row.
DEV int swz8(int row) { return ((row ^ (row >> 3)) & 7) << 4; }

constexpr float QSCL = (float)(1.4426950408889634 / 5.656854249492381);  // log2(e)/sqrt(32)

// ---------------------------------------------------------------------------
// Mask preprocessing: bits[row][w] (u64, bit set = masked).  Quirks:
//  - row with NO masked entries: set diag bit   (torch need_fix)
//  - row with ALL masked: clear diag bit        (== torch's diag-score-0 fixup
//    in softmax-weight space: single finite score -> weight 1 on diag)
// ---------------------------------------------------------------------------
__global__ __launch_bounds__(256) void gace_mask_k(
    const float* __restrict__ am, unsigned long long* __restrict__ bits)
{
    const int tid = threadIdx.x, wid = tid >> 6, l = tid & 63;
    const int row = blockIdx.x * 4 + wid;              // 0..8191
    const float* mrow = am + (size_t)row * 2048;
    unsigned long long myword = 0, orAll = 0, andAll = ~0ull;
#pragma unroll 4
    for (int w = 0; w < 32; ++w) {
        unsigned long long bal = __ballot(mrow[w * 64 + l] > 0.5f);
        if (w == l) myword = bal;
        orAll |= bal; andAll &= bal;
    }
    const int lrow = row & 2047;
    const int dw = lrow >> 6, dbit = lrow & 63;
    if (l == dw) {
        if (orAll == 0ull) myword |= (1ull << dbit);
        else if (andAll == ~0ull) myword &= ~(1ull << dbit);
    }
    if (l < 32) bits[(size_t)row * 32 + l] = myword;
}

// ---------------------------------------------------------------------------
// Weight prep: f32 [k][n] -> bf16 [n][k]; QSCL folded into qW;
// bcat = concat(qb*QSCL, kb, vb) per layer.
// wbf layer block (shorts): q 16384 | k 16384 | v 16384 | o 16384 | f1 32768 | f2 32768
// ---------------------------------------------------------------------------
__global__ __launch_bounds__(256) void gace_prep_k(
    const float* __restrict__ qW, const float* __restrict__ kW,
    const float* __restrict__ vW, const float* __restrict__ oW,
    const float* __restrict__ f1W, const float* __restrict__ f2W,
    const float* __restrict__ qb, const float* __restrict__ kb,
    const float* __restrict__ vb,
    unsigned short* __restrict__ wbf, float* __restrict__ bcat)
{
    const int y = blockIdx.y;
    const int idx = blockIdx.x * 256 + threadIdx.x;
    if (y == 6) {
        if (idx < 2 * 384) {
            const int i = idx / 384, j = idx % 384;
            float v;
            if (j < 128)      v = qb[i * 128 + j] * QSCL;
            else if (j < 256) v = kb[i * 128 + j - 128];
            else              v = vb[i * 128 + j - 256];
            bcat[idx] = v;
        }
        return;
    }
    const float* src; int K_, N_, off; float scl = 1.0f;
    switch (y) {
        case 0:  src = qW;  K_ = 128; N_ = 128; off = 0;      scl = QSCL; break;
        case 1:  src = kW;  K_ = 128; N_ = 128; off = 16384;  break;
        case 2:  src = vW;  K_ = 128; N_ = 128; off = 32768;  break;
        case 3:  src = oW;  K_ = 128; N_ = 128; off = 49152;  break;
        case 4:  src = f1W; K_ = 128; N_ = 256; off = 65536;  break;
        default: src = f2W; K_ = 256; N_ = 128; off = 98304;  break;
    }
    const int per = K_ * N_;
    if (idx >= 2 * per) return;
    const int i = idx / per, rem = idx % per;
    const int n = rem / K_, k = rem % K_;
    wbf[(size_t)i * 131072 + off + n * K_ + k] = f2bf(src[(size_t)i * per + k * N_ + n] * scl);
}

// ---------------------------------------------------------------------------
// ctx = task@tW + priv@pW + dag@dW (+biases), then pre-LN -> x (f32)
// wave per row, 4 waves/block
// ---------------------------------------------------------------------------
__global__ __launch_bounds__(256) void gace_ctxln_k(
    const float* __restrict__ task, const float* __restrict__ priv, const float* __restrict__ dag,
    const float* __restrict__ tW, const float* __restrict__ tb,
    const float* __restrict__ pW, const float* __restrict__ pb,
    const float* __restrict__ dW, const float* __restrict__ db,
    const float* __restrict__ gam, const float* __restrict__ bet,
    float* __restrict__ x)
{
    const int tid = threadIdx.x, wid = tid >> 6, l = tid & 63;
    const int row = blockIdx.x * 4 + wid;
    const int d0 = l, d1 = l + 64;
    float a0 = tb[d0] + pb[d0] + db[d0];
    float a1 = tb[d1] + pb[d1] + db[d1];
    const float* tf = task + (size_t)row * 15;
#pragma unroll
    for (int j = 0; j < 15; ++j) { const float t = tf[j]; a0 += t * tW[j * 128 + d0]; a1 += t * tW[j * 128 + d1]; }
    const float* pf = priv + (size_t)row * 6;
#pragma unroll
    for (int j = 0; j < 6; ++j) { const float t = pf[j]; a0 += t * pW[j * 128 + d0]; a1 += t * pW[j * 128 + d1]; }
    const float* df = dag + (size_t)row * 4;
#pragma unroll
    for (int j = 0; j < 4; ++j) { const float t = df[j]; a0 += t * dW[j * 128 + d0]; a1 += t * dW[j * 128 + d1]; }
    const float s = wave_sum64(a0 + a1);
    const float mean = s * (1.f / 128.f);
    const float e0 = a0 - mean, e1 = a1 - mean;
    const float s2 = wave_sum64(e0 * e0 + e1 * e1);
    const float rs = rsqrtf(s2 * (1.f / 128.f) + 1e-5f);
    x[(size_t)row * 128 + d0] = e0 * rs * gam[d0] + bet[d0];
    x[(size_t)row * 128 + d1] = e1 * rs * gam[d1] + bet[d1];
}

// ---------------------------------------------------------------------------
// Mega GEMM: C[M,N] = A' @ Wt^T + bias, 16x16x32 mfma, no LDS.
// PRO: 0 = A bf16 loads; 1 = fused LayerNorm(xin) -> frags; 2 = fused
//      split-combine(Op,ml) -> frags (attention output).
// EPI: 0 = store bf16; 1 = exact-GELU store bf16; 2 = += into f32 xadd (N=128)
// Block: 4 waves x (16 m-rows x 64 n-cols); grid (M/64, Ntot/64).
// ---------------------------------------------------------------------------
template<int PRO, int EPI, int KD>
__global__ __launch_bounds__(256) void gace_mega_k(
    const unsigned short* __restrict__ A, int lda,
    const float* __restrict__ xin,
    const float* __restrict__ Op, const float* __restrict__ ml,
    const float* __restrict__ gam, const float* __restrict__ bet,
    const unsigned short* __restrict__ Wt,
    const float* __restrict__ bias,
    unsigned short* __restrict__ outb, int ldo,
    float* __restrict__ xadd)
{
    const int tid = threadIdx.x;
    const int wid = tid >> 6, l = tid & 63;
    const int g = (l >> 4) & 3, c16 = l & 15;
    const int m0 = blockIdx.x * 64 + wid * 16;
    const int n0 = blockIdx.y * 64;
    const int arow = m0 + c16;
    constexpr int NKC = KD / 32;

    s16x8 af[NKC];
    if (PRO == 0) {
#pragma unroll
        for (int kc = 0; kc < NKC; ++kc)
            af[kc] = *(const s16x8*)&A[(size_t)arow * lda + kc * 32 + 8 * g];
    } else if (PRO == 1) {
        float v[4][8];
#pragma unroll
        for (int kc = 0; kc < 4; ++kc) {
            const f32x4 a0 = *(const f32x4*)&xin[(size_t)arow * 128 + kc * 32 + 8 * g];
            const f32x4 a1 = *(const f32x4*)&xin[(size_t)arow * 128 + kc * 32 + 8 * g + 4];
#pragma unroll
            for (int e = 0; e < 4; ++e) { v[kc][e] = a0[e]; v[kc][4 + e] = a1[e]; }
        }
        float s = 0.f;
#pragma unroll
        for (int kc = 0; kc < 4; ++kc)
#pragma unroll
            for (int e = 0; e < 8; ++e) s += v[kc][e];
        s += __shfl_xor(s, 16, 64); s += __shfl_xor(s, 32, 64);
        const float mean = s * (1.f / 128.f);
        float s2 = 0.f;
#pragma unroll
        for (int kc = 0; kc < 4; ++kc)
#pragma unroll
            for (int e = 0; e < 8; ++e) { const float d = v[kc][e] - mean; s2 += d * d; }
        s2 += __shfl_xor(s2, 16, 64); s2 += __shfl_xor(s2, 32, 64);
        const float rs = rsqrtf(s2 * (1.f / 128.f) + 1e-5f);
#pragma unroll
        for (int kc = 0; kc < 4; ++kc) {
            union { s16x8 v8; unsigned d[4]; } pk;
#pragma unroll
            for (int j = 0; j < 4; ++j) {
                const int col = kc * 32 + 8 * g + 2 * j;
                const float x0 = (v[kc][2 * j] - mean) * rs * gam[col] + bet[col];
                const float x1 = (v[kc][2 * j + 1] - mean) * rs * gam[col + 1] + bet[col + 1];
                pk.d[j] = f2bf2(x0, x1);
            }
            af[kc] = pk.v8;
        }
    } else {
        // combine 4 KV-splits: att = (sum_s O_s) / (sum_s l_s); head h == kc
#pragma unroll
        for (int kc = 0; kc < 4; ++kc) {
            float o[8];
#pragma unroll
            for (int e = 0; e < 8; ++e) o[e] = 0.f;
            float Ls = 0.f;
#pragma unroll
            for (int sp = 0; sp < 4; ++sp) {
                const size_t ro = (size_t)sp * 8192 + arow;
                const f32x4 a0 = *(const f32x4*)&Op[ro * 128 + kc * 32 + 8 * g];
                const f32x4 a1 = *(const f32x4*)&Op[ro * 128 + kc * 32 + 8 * g + 4];
#pragma unroll
                for (int e = 0; e < 4; ++e) { o[e] += a0[e]; o[4 + e] += a1[e]; }
                Ls += ml[ro * 4 + kc];
            }
            const float inv = 1.f / Ls;
            union { s16x8 v8; unsigned d[4]; } pk;
#pragma unroll
            for (int j = 0; j < 4; ++j) pk.d[j] = f2bf2(o[2 * j] * inv, o[2 * j + 1] * inv);
            af[kc] = pk.v8;
        }
    }

    f32x4 acc[4];
#pragma unroll
    for (int i = 0; i < 4; ++i) acc[i] = f32x4{0.f, 0.f, 0.f, 0.f};
#pragma unroll
    for (int ns = 0; ns < 4; ++ns) {
        const unsigned short* wrow = Wt + (size_t)(n0 + 16 * ns + c16) * KD;
#pragma unroll
        for (int kc = 0; kc < NKC; ++kc) {
            const s16x8 bfv = *(const s16x8*)&wrow[kc * 32 + 8 * g];
            acc[ns] = __builtin_amdgcn_mfma_f32_16x16x32_bf16(
                as_bf16(af[kc]), as_bf16(bfv), acc[ns], 0, 0, 0);
        }
    }
#pragma unroll
    for (int ns = 0; ns < 4; ++ns) {
        const int n = n0 + ns * 16 + c16;
        const float bv = bias[n];
#pragma unroll
        for (int r = 0; r < 4; ++r) {
            const int row = m0 + 4 * g + r;
            float v = acc[ns][r] + bv;
            if (EPI == 1) v = v * 0.5f * (1.0f + erff(v * 0.70710678118654752f));
            if (EPI == 2) xadd[(size_t)row * 128 + n] += v;
            else          outb[(size_t)row * ldo + n] = f2bf(v);
        }
    }
}

// ---------------------------------------------------------------------------
// Flash attention v4: 32x32x16 mfma, swapped QK^T, max-free base-2 softmax.
// K staged with block-swap permutation pi (x^12 if (x&12) in {4,8}) so the
// QK^T output registers ARE the PV A-fragments (zero exchange).
// KV-split x4; outputs unnormalized O (f32) + per-row l sums.
// Block: 4 waves x 32 q-rows = 128 q; 8 KV tiles of 64.
// ---------------------------------------------------------------------------
__global__ __launch_bounds__(256) void gace_flash4_k(
    const unsigned short* __restrict__ QKV,
    const unsigned long long* __restrict__ bits,
    float* __restrict__ Op, float* __restrict__ ml)
{
    __shared__ __align__(16) unsigned short Ks[64 * 40];   // [perm kv][dh], pitch 40
    __shared__ __align__(16) char VtB[32 * 128];           // [dh][kv] bf16, swizzled

    const int tid = threadIdx.x;
    const int wid = tid >> 6, l = tid & 63;
    const int c32 = l & 31, hi = l >> 5;
    const int bid = blockIdx.x;
    const int split = bid & 3, qc = (bid >> 2) & 15, h = (bid >> 6) & 3, b = bid >> 8;
    const size_t base = (size_t)b * 2048;
    const int qb0 = qc * 128 + wid * 32;
    const int q = qb0 + c32;

    // Q B-frags (kc 0,1): elem e -> dh = 16*kc + 8*hi + e   (Q pre-scaled)
    const unsigned short* qrow = &QKV[(base + q) * 384 + h * 32];
    const s16x8 qf0 = *(const s16x8*)&qrow[8 * hi];
    const s16x8 qf1 = *(const s16x8*)&qrow[16 + 8 * hi];

    f32x16 oacc, zv;
#pragma unroll
    for (int i = 0; i < 16; ++i) { oacc[i] = 0.f; zv[i] = 0.f; }
    float l_ = 0.f;

    // staging
    const int sr = tid >> 2;                // kv row 0..63
    const int se = (tid & 3) << 3;          // dh elem 0,8,16,24
    const int lowr = sr & 31, t12 = lowr & 12;
    const int prow = (sr & 32) | (((t12 == 4) | (t12 == 8)) ? (lowr ^ 12) : lowr);
    unsigned short* kdst = &Ks[prow * 40 + se];
    int voff[8];
#pragma unroll
    for (int j = 0; j < 8; ++j) {
        const int row = se + j;
        voff[j] = row * 128 + ((2 * sr) ^ swz8(row));
    }
    const int vswz = swz8(c32);
    const unsigned short* kbase = &QKV[base * 384 + 128 + h * 32 + se];
    const unsigned short* vbase = kbase + 128;
    const unsigned long long* bq = &bits[(base + q) * 32 + split * 8];

    const int kv0 = split * 512;
    s16x8 kreg = *(const s16x8*)&kbase[(size_t)(kv0 + sr) * 384];
    s16x8 vreg = *(const s16x8*)&vbase[(size_t)(kv0 + sr) * 384];
    unsigned long long wb = bq[0];
    *(s16x8*)kdst = kreg;
    {
        union { s16x8 v; unsigned short u[8]; } vv; vv.v = vreg;
#pragma unroll
        for (int j = 0; j < 8; ++j) *(unsigned short*)&VtB[voff[j]] = vv.u[j];
    }
    __syncthreads();

    for (int t = 0; t < 8; ++t) {
        unsigned long long wbn = 0;
        if (t < 7) {
            const int kvn = kv0 + (t + 1) * 64;
            kreg = *(const s16x8*)&kbase[(size_t)(kvn + sr) * 384];
            vreg = *(const s16x8*)&vbase[(size_t)(kvn + sr) * 384];
            wbn = bq[t + 1];
        }
        const unsigned long long wbs = wb >> (8 * hi);
        const unsigned wlo = (unsigned)wbs, whiw = (unsigned)(wbs >> 32);
#pragma unroll
        for (int H = 0; H < 2; ++H) {
            const unsigned short* krow = &Ks[(32 * H + c32) * 40 + 8 * hi];
            f32x16 sac = __builtin_amdgcn_mfma_f32_32x32x16_bf16(
                as_bf16(*(const s16x8*)&krow[0]), as_bf16(qf0), zv, 0, 0, 0);
            sac = __builtin_amdgcn_mfma_f32_32x32x16_bf16(
                as_bf16(*(const s16x8*)&krow[16]), as_bf16(qf1), sac, 0, 0, 0);
            const unsigned word = (H == 0) ? wlo : whiw;
#pragma unroll
            for (int ch = 0; ch < 2; ++ch) {
                const int c = 2 * H + ch;          // global kv chunk 0..3
                const int bb = ch * 16;
                float p[8];
#pragma unroll
                for (int e = 0; e < 8; ++e) {
                    const float pe = exp2f(sac[ch * 8 + e]);
                    p[e] = ((word >> (bb + e)) & 1u) ? 0.f : pe;
                }
                l_ += ((p[0] + p[1]) + (p[2] + p[3])) + ((p[4] + p[5]) + (p[6] + p[7]));
                union { s16x8 v; unsigned d[4]; } pa;
#pragma unroll
                for (int j = 0; j < 4; ++j)
                    asm("v_cvt_pk_bf16_f32 %0, %1, %2"
                        : "=v"(pa.d[j]) : "v"(p[2 * j]), "v"(p[2 * j + 1]));
                const s16x8 vf = *(const s16x8*)&VtB[c32 * 128 + ((32 * c + 16 * hi) ^ vswz)];
                oacc = __builtin_amdgcn_mfma_f32_32x32x16_bf16(
                    as_bf16(pa.v), as_bf16(vf), oacc, 0, 0, 0);
            }
        }
        if (t < 7) {
            __syncthreads();
            *(s16x8*)kdst = kreg;
            union { s16x8 v; unsigned short u[8]; } vv; vv.v = vreg;
#pragma unroll
            for (int j = 0; j < 8; ++j) *(unsigned short*)&VtB[voff[j]] = vv.u[j];
            __syncthreads();
            wb = wbn;
        }
    }
    // epilogue
    l_ += __shfl_xor(l_, 32, 64);
    float* orow = &Op[((size_t)split * 8192 + base + qb0) * 128 + h * 32 + c32];
#pragma unroll
    for (int r = 0; r < 16; ++r) {
        const int qoff = (r & 3) + 8 * (r >> 2) + 4 * hi;
        orow[(size_t)qoff * 128] = oacc[r];
    }
    if (l < 32) ml[((size_t)split * 8192 + base + q) * 4 + h] = l_;
}

// ---------------------------------------------------------------------------
// Tail A: post-LN each row, partial-sum 64 rows per block
// ---------------------------------------------------------------------------
__global__ __launch_bounds__(256) void gace_tailA_k(
    const float* __restrict__ x, const float* __restrict__ gam, const float* __restrict__ bet,
    float* __restrict__ partial)
{
    const int tid = threadIdx.x, wid = tid >> 6, l = tid & 63;
    const int row0 = blockIdx.x * 64 + wid * 16;
    const float g0 = gam[l], g1v = gam[l + 64], b0 = bet[l], b1 = bet[l + 64];
    float a0 = 0.f, a1 = 0.f;
    for (int rr = 0; rr < 16; ++rr) {
        const float* xr = x + (size_t)(row0 + rr) * 128;
        const float v0 = xr[l], v1 = xr[l + 64];
        const float s = wave_sum64(v0 + v1);
        const float mean = s * (1.f / 128.f);
        const float d0 = v0 - mean, d1 = v1 - mean;
        const float s2 = wave_sum64(d0 * d0 + d1 * d1);
        const float rs = rsqrtf(s2 * (1.f / 128.f) + 1e-5f);
        a0 += d0 * rs * g0 + b0;
        a1 += d1 * rs * g1v + b1;
    }
    __shared__ float red[4][128];
    red[wid][l] = a0;
    red[wid][l + 64] = a1;
    __syncthreads();
    if (tid < 128) {
        partial[(size_t)blockIdx.x * 128 + tid] =
            red[0][tid] + red[1][tid] + red[2][tid] + red[3][tid];
    }
}

// ---------------------------------------------------------------------------
// Tail B: fused = mean + 0.1*lg; out = fused @ out_W + out_b
// ---------------------------------------------------------------------------
__global__ __launch_bounds__(128) void gace_tailB_k(
    const float* __restrict__ partial, const float* __restrict__ lg,
    const float* __restrict__ oW, const float* __restrict__ obv,
    float* __restrict__ out)
{
    const int tid = threadIdx.x;
    __shared__ float fused[4][128];
#pragma unroll
    for (int b2 = 0; b2 < 4; ++b2) {
        float s = 0.f;
        for (int c = 0; c < 32; ++c) s += partial[(size_t)(b2 * 32 + c) * 128 + tid];
        fused[b2][tid] = s * (1.f / 2048.f) + 0.1f * lg[b2 * 128 + tid];
    }
    __syncthreads();
#pragma unroll
    for (int b2 = 0; b2 < 4; ++b2) {
        float r = obv[tid];
        for (int d2 = 0; d2 < 128; ++d2) r += fused[b2][d2] * oW[d2 * 128 + tid];
        out[b2 * 128 + tid] = r;
    }
}

// ---------------------------------------------------------------------------
extern "C" void kernel_launch(void* const* d_in, const int* in_sizes, int n_in,
                              void* d_out, int out_size, void* d_ws, size_t ws_size,
                              hipStream_t stream)
{
    (void)in_sizes; (void)n_in; (void)out_size; (void)ws_size;
    const float* local_global = (const float*)d_in[0];
    const float* task   = (const float*)d_in[1];
    const float* priv   = (const float*)d_in[2];
    const float* dag    = (const float*)d_in[3];
    const float* amask  = (const float*)d_in[4];
    const float* task_W = (const float*)d_in[5];
    const float* task_b = (const float*)d_in[6];
    const float* priv_W = (const float*)d_in[7];
    const float* priv_b = (const float*)d_in[8];
    const float* dag_W  = (const float*)d_in[9];
    const float* dag_b  = (const float*)d_in[10];
    const float* pre_g  = (const float*)d_in[11];
    const float* pre_b  = (const float*)d_in[12];
    const float* post_g = (const float*)d_in[13];
    const float* post_b = (const float*)d_in[14];
    const float* out_W  = (const float*)d_in[15];
    const float* out_b  = (const float*)d_in[16];
    const float* qW = (const float*)d_in[17];
    const float* qb = (const float*)d_in[18];
    const float* kW = (const float*)d_in[19];
    const float* kb = (const float*)d_in[20];
    const float* vW = (const float*)d_in[21];
    const float* vb = (const float*)d_in[22];
    const float* oW = (const float*)d_in[23];
    const float* ob = (const float*)d_in[24];
    const float* n1g = (const float*)d_in[25];
    const float* n1b = (const float*)d_in[26];
    const float* n2g = (const float*)d_in[27];
    const float* n2b = (const float*)d_in[28];
    const float* f1W = (const float*)d_in[29];
    const float* f1b = (const float*)d_in[30];
    const float* f2W = (const float*)d_in[31];
    const float* f2b = (const float*)d_in[32];

    char* ws = (char*)d_ws;
    size_t off = 0;
    auto carve = [&](size_t sz) {
        void* p = ws + off;
        off += (sz + 255) & ~(size_t)255;
        return p;
    };
    unsigned long long* bits = (unsigned long long*)carve(8192ull * 32 * 8);  // 2 MB
    float*          x    = (float*)carve(8192ull * 128 * 4);                   // 4 MB
    unsigned short* qkv  = (unsigned short*)carve(8192ull * 384 * 2);          // 6 MB
    unsigned short* g1   = (unsigned short*)carve(8192ull * 256 * 2);          // 4 MB
    float*          part = (float*)carve(128ull * 128 * 4);
    float*          Op   = (float*)carve(4ull * 8192 * 128 * 4);               // 16 MB
    float*          mlb  = (float*)carve(4ull * 8192 * 4 * 4);                 // 512 KB
    unsigned short* wbf  = (unsigned short*)carve(2ull * 131072 * 2);          // 512 KB
    float*          bcat = (float*)carve(2ull * 384 * 4);

    gace_prep_k<<<dim3(256, 7), 256, 0, stream>>>(qW, kW, vW, oW, f1W, f2W,
                                                  qb, kb, vb, wbf, bcat);
    gace_mask_k<<<2048, 256, 0, stream>>>(amask, bits);
    gace_ctxln_k<<<2048, 256, 0, stream>>>(task, priv, dag, task_W, task_b,
                                           priv_W, priv_b, dag_W, dag_b,
                                           pre_g, pre_b, x);
    for (int i = 0; i < 2; ++i) {
        const unsigned short* wl = wbf + (size_t)i * 131072;
        // qkv projection with fused LN1
        gace_mega_k<1, 0, 128><<<dim3(128, 6), 256, 0, stream>>>(
            nullptr, 0, x, nullptr, nullptr, n1g + i * 128, n1b + i * 128,
            wl, bcat + i * 384, qkv, 384, nullptr);
        gace_flash4_k<<<1024, 256, 0, stream>>>(qkv, bits, Op, mlb);
        // o-proj with fused split-combine, += x
        gace_mega_k<2, 2, 128><<<dim3(128, 2), 256, 0, stream>>>(
            nullptr, 0, nullptr, Op, mlb, nullptr, nullptr,
            wl + 49152, ob + i * 128, nullptr, 0, x);
        // FF1 with fused LN2 + GELU
        gace_mega_k<1, 1, 128><<<dim3(128, 4), 256, 0, stream>>>(
            nullptr, 0, x, nullptr, nullptr, n2g + i * 128, n2b + i * 128,
            wl + 65536, f1b + i * 256, g1, 256, nullptr);
        // FF2, += x
        gace_mega_k<0, 2, 256><<<dim3(128, 2), 256, 0, stream>>>(
            g1, 256, nullptr, nullptr, nullptr, nullptr, nullptr,
            wl + 98304, f2b + i * 128, nullptr, 0, x);
    }
    gace_tailA_k<<<128, 256, 0, stream>>>(x, post_g, post_b, part);
    gace_tailB_k<<<1, 128, 0, stream>>>(part, local_global, out_W, out_b, (float*)d_out);
}